// Round 1
// baseline (1863.032 us; speedup 1.0000x reference)
//
#include <hip/hip_runtime.h>
#include <math.h>

#define DIM 96
#define NHD 3
#define HD 32
#define NWT 343          // tokens per window
#define NWIN 128         // b * windows
#define TOK 43904        // total tokens = 2*28^3
#define NBIAS 2197       // (2*7-1)^3
#define SCALE 0.17677669529663687f

__device__ __forceinline__ float waveReduceSum(float v) {
    #pragma unroll
    for (int off = 32; off > 0; off >>= 1) v += __shfl_xor(v, off, 64);
    return v;
}

// ---------------- K1: LN1 + roll(-shift) + window partition -----------------
// one wave per output (window-order) token; gathers source row, LN, writes contiguous
__global__ void __launch_bounds__(256) k_ln_part(
        const float* __restrict__ x, const float* __restrict__ g,
        const float* __restrict__ bta, float* __restrict__ hw, int shift) {
    int wave = (blockIdx.x * blockDim.x + threadIdx.x) >> 6;
    int lane = threadIdx.x & 63;
    if (wave >= TOK) return;
    int bw = wave / NWT, n = wave % NWT;
    int b = bw >> 6, win = bw & 63;
    int wdi = win >> 4, whi = (win >> 2) & 3, wwi = win & 3;
    int d = n / 49, h = (n / 7) % 7, w = n % 7;
    int gd = wdi * 7 + d, gh = whi * 7 + h, gw = wwi * 7 + w;
    int sd = (gd + shift) % 28, sh = (gh + shift) % 28, sw = (gw + shift) % 28;
    const float* row = x + (((size_t)(b * 28 + sd) * 28 + sh) * 28 + sw) * DIM;
    float e0 = row[lane];
    float e1 = (lane < 32) ? row[64 + lane] : 0.0f;
    float s  = waveReduceSum(e0 + e1);
    float mu = s * (1.0f / 96.0f);
    float s2 = waveReduceSum(e0 * e0 + e1 * e1);
    float var = s2 * (1.0f / 96.0f) - mu * mu;
    float rstd = rsqrtf(var + 1e-5f);
    float* dst = hw + (size_t)wave * DIM;
    dst[lane] = (e0 - mu) * rstd * g[lane] + bta[lane];
    if (lane < 32) dst[64 + lane] = (e1 - mu) * rstd * g[64 + lane] + bta[64 + lane];
}

// ---------------- K2: QKV row-GEMM, 8 tokens/block ---------------------------
__global__ void __launch_bounds__(256) k_qkv(
        const float* __restrict__ hw, const float* __restrict__ Wt,
        const float* __restrict__ bias, float* __restrict__ q,
        float* __restrict__ k, float* __restrict__ v) {
    __shared__ float xs[8 * 96];
    int base = blockIdx.x * 8;
    for (int i = threadIdx.x; i < 8 * 96; i += 256)
        xs[i] = hw[(size_t)base * 96 + i];
    __syncthreads();
    for (int c = threadIdx.x; c < 288; c += 256) {
        float acc[8];
        #pragma unroll
        for (int t = 0; t < 8; ++t) acc[t] = 0.f;
        const float* wr = Wt + c * 96;
        for (int kk = 0; kk < 96; ++kk) {
            float wv = wr[kk];
            #pragma unroll
            for (int t = 0; t < 8; ++t) acc[t] += xs[t * 96 + kk] * wv;
        }
        int which = c / 96, hdc = c % 96;
        int head = hdc >> 5, hd = hdc & 31;
        float bb = bias[c];
        float sc = (which == 0) ? SCALE : 1.0f;
        float* dstp = (which == 0) ? q : (which == 1) ? k : v;
        #pragma unroll
        for (int t = 0; t < 8; ++t) {
            int tok = base + t;
            int bw = tok / NWT, n = tok % NWT;
            dstp[(((size_t)bw * NHD + head) * NWT + n) * HD + hd] = (acc[t] + bb) * sc;
        }
    }
}

// ---------------- K3: attention, one block per (window, head) ----------------
__global__ void __launch_bounds__(256) k_attn(
        const float* __restrict__ q, const float* __restrict__ k,
        const float* __restrict__ v, const float* __restrict__ rel,
        float* __restrict__ o, int shifted) {
    __shared__ float ks[NWT * HD];   // 43904 B
    __shared__ float relh[NBIAS];    //  8788 B
    __shared__ int   cnt[NWT];       //  1372 B
    __shared__ int   jcode[NWT];     //  1372 B
    int bw = blockIdx.x / NHD, head = blockIdx.x % NHD;
    size_t hb = ((size_t)bw * NHD + head) * NWT * HD;
    for (int i = threadIdx.x; i < NWT * HD; i += 256) ks[i] = k[hb + i];
    for (int i = threadIdx.x; i < NBIAS; i += 256) relh[i] = rel[i * NHD + head];
    int win = bw & 63;
    int wdi = win >> 4, whi = (win >> 2) & 3, wwi = win & 3;
    for (int i = threadIdx.x; i < NWT; i += 256) {
        int d = i / 49, h = (i / 7) % 7, w = i % 7;
        int gd = wdi * 7 + d, gh = whi * 7 + h, gw = wwi * 7 + w;
        int rd = (gd < 21) ? 0 : ((gd < 25) ? 1 : 2);
        int rh = (gh < 21) ? 0 : ((gh < 25) ? 1 : 2);
        int rw = (gw < 21) ? 0 : ((gw < 25) ? 1 : 2);
        cnt[i] = rd * 9 + rh * 3 + rw;
        jcode[i] = d * 169 + h * 13 + w;
    }
    __syncthreads();
    for (int r = threadIdx.x; r < NWT; r += 256) {
        float qr[HD];
        const float* qp = q + hb + (size_t)r * HD;
        #pragma unroll
        for (int d2 = 0; d2 < HD; ++d2) qr[d2] = qp[d2];
        int rd0 = r / 49, rh0 = (r / 7) % 7, rw0 = r % 7;
        int rbase = (rd0 + 6) * 169 + (rh0 + 6) * 13 + (rw0 + 6);
        int cr = cnt[r];
        // pass 1: row max
        float m = -1e30f;
        for (int j = 0; j < NWT; ++j) {
            float s = 0.f;
            #pragma unroll
            for (int d2 = 0; d2 < HD; ++d2) s += qr[d2] * ks[j * HD + d2];
            s += relh[rbase - jcode[j]];
            if (shifted && cnt[j] != cr) s -= 100.0f;
            m = fmaxf(m, s);
        }
        // pass 2: exp-sum + PV
        float acc[HD];
        #pragma unroll
        for (int d2 = 0; d2 < HD; ++d2) acc[d2] = 0.f;
        float denom = 0.f;
        const float* vp = v + hb;
        for (int j = 0; j < NWT; ++j) {
            float s = 0.f;
            #pragma unroll
            for (int d2 = 0; d2 < HD; ++d2) s += qr[d2] * ks[j * HD + d2];
            s += relh[rbase - jcode[j]];
            if (shifted && cnt[j] != cr) s -= 100.0f;
            float p = __expf(s - m);
            denom += p;
            #pragma unroll
            for (int d2 = 0; d2 < HD; ++d2) acc[d2] += p * vp[j * HD + d2];
        }
        float inv = 1.0f / denom;
        float* op = o + ((size_t)(bw * NWT + r)) * DIM + head * HD;
        #pragma unroll
        for (int d2 = 0; d2 < HD; ++d2) op[d2] = acc[d2] * inv;
    }
}

// ---------------- K4: proj + window reverse + roll(+shift) + residual --------
__global__ void __launch_bounds__(256) k_proj(
        const float* __restrict__ ao, const float* __restrict__ W,
        const float* __restrict__ bias, const float* __restrict__ xin,
        float* __restrict__ xout, int shift) {
    __shared__ float as[16 * 96];
    __shared__ int tsrc[16];
    int base = blockIdx.x * 16;
    if (threadIdx.x < 16) {
        int tok = base + threadIdx.x;
        int b = tok / 21952, rem = tok % 21952;
        int D = rem / 784, H = (rem / 28) % 28, Wc = rem % 28;
        int gd = (D - shift + 28) % 28, gh = (H - shift + 28) % 28, gw = (Wc - shift + 28) % 28;
        int win = ((gd / 7) * 4 + (gh / 7)) * 4 + (gw / 7);
        int n = ((gd % 7) * 7 + (gh % 7)) * 7 + (gw % 7);
        tsrc[threadIdx.x] = (b * 64 + win) * NWT + n;
    }
    __syncthreads();
    for (int i = threadIdx.x; i < 16 * 96; i += 256) {
        int tl = i / 96, cc = i % 96;
        as[i] = ao[(size_t)tsrc[tl] * 96 + cc];
    }
    __syncthreads();
    int half = threadIdx.x / 128;
    int c = threadIdx.x % 128;
    if (c < 96) {
        float acc[8];
        #pragma unroll
        for (int t = 0; t < 8; ++t) acc[t] = 0.f;
        const float* wr = W + c * 96;
        const float* asr = as + half * 8 * 96;
        for (int kk = 0; kk < 96; ++kk) {
            float wv = wr[kk];
            #pragma unroll
            for (int t = 0; t < 8; ++t) acc[t] += asr[t * 96 + kk] * wv;
        }
        float bb = bias[c];
        #pragma unroll
        for (int t = 0; t < 8; ++t) {
            size_t off = (size_t)(base + half * 8 + t) * 96 + c;
            xout[off] = xin[off] + acc[t] + bb;
        }
    }
}

// ---------------- K5: LN2 + fc1 + GELU(exact) + fc2 + residual ---------------
__global__ void __launch_bounds__(256) k_mlp(
        const float* __restrict__ xin, float* __restrict__ xout,
        const float* __restrict__ g2, const float* __restrict__ b2,
        const float* __restrict__ w1, const float* __restrict__ bb1,
        const float* __restrict__ w2, const float* __restrict__ bb2) {
    __shared__ float xs[8 * 96];
    __shared__ float ln[8 * 96];
    __shared__ float hid[8 * 384];
    __shared__ float mu[8], rs[8];
    int base = blockIdx.x * 8;
    for (int i = threadIdx.x; i < 768; i += 256) xs[i] = xin[(size_t)base * 96 + i];
    __syncthreads();
    if (threadIdx.x < 8) {
        float s = 0.f, s2 = 0.f;
        const float* r = xs + threadIdx.x * 96;
        for (int kk = 0; kk < 96; ++kk) { float vv = r[kk]; s += vv; s2 += vv * vv; }
        float m = s * (1.0f / 96.0f);
        mu[threadIdx.x] = m;
        rs[threadIdx.x] = rsqrtf(s2 * (1.0f / 96.0f) - m * m + 1e-5f);
    }
    __syncthreads();
    for (int i = threadIdx.x; i < 768; i += 256) {
        int t = i / 96, cc = i % 96;
        ln[i] = (xs[i] - mu[t]) * rs[t] * g2[cc] + b2[cc];
    }
    __syncthreads();
    for (int c = threadIdx.x; c < 384; c += 256) {
        float acc[8];
        #pragma unroll
        for (int t = 0; t < 8; ++t) acc[t] = 0.f;
        const float* wr = w1 + c * 96;
        for (int kk = 0; kk < 96; ++kk) {
            float wv = wr[kk];
            #pragma unroll
            for (int t = 0; t < 8; ++t) acc[t] += ln[t * 96 + kk] * wv;
        }
        float bb = bb1[c];
        #pragma unroll
        for (int t = 0; t < 8; ++t) {
            float v2 = acc[t] + bb;
            hid[t * 384 + c] = 0.5f * v2 * (1.0f + erff(v2 * 0.70710678118654752f));
        }
    }
    __syncthreads();
    int gidx = threadIdx.x / 96;      // groups 0,1 active (tokens 0-3 / 4-7)
    int c = threadIdx.x % 96;
    if (gidx < 2) {
        float acc[4];
        #pragma unroll
        for (int t = 0; t < 4; ++t) acc[t] = 0.f;
        const float* wr = w2 + c * 384;
        const float* hr = hid + gidx * 4 * 384;
        for (int kk = 0; kk < 384; ++kk) {
            float wv = wr[kk];
            #pragma unroll
            for (int t = 0; t < 4; ++t) acc[t] += hr[t * 384 + kk] * wv;
        }
        float bb = bb2[c];
        #pragma unroll
        for (int t = 0; t < 4; ++t) {
            size_t off = (size_t)(base + gidx * 4 + t) * 96 + c;
            xout[off] = xs[(gidx * 4 + t) * 96 + c] + acc[t] + bb;
        }
    }
}

extern "C" void kernel_launch(void* const* d_in, const int* in_sizes, int n_in,
                              void* d_out, int out_size, void* d_ws, size_t ws_size,
                              hipStream_t stream) {
    const float* x     = (const float*)d_in[0];
    const float* n1g   = (const float*)d_in[1];
    const float* n1b   = (const float*)d_in[2];
    const float* qkvw  = (const float*)d_in[3];
    const float* qkvb  = (const float*)d_in[4];
    const float* relb  = (const float*)d_in[5];
    const float* projw = (const float*)d_in[6];
    const float* projb = (const float*)d_in[7];
    const float* n2g   = (const float*)d_in[8];
    const float* n2b   = (const float*)d_in[9];
    const float* fc1w  = (const float*)d_in[10];
    const float* fc1b  = (const float*)d_in[11];
    const float* fc2w  = (const float*)d_in[12];
    const float* fc2b  = (const float*)d_in[13];
    float* out = (float*)d_out;

    const size_t NEL = (size_t)TOK * DIM;   // 4,214,784
    float* buf_x = (float*)d_ws;            // running x
    float* buf_h = buf_x + NEL;             // windowed LN output; reused as attn output
    float* bq    = buf_h + NEL;
    float* bk    = bq + NEL;
    float* bv    = bk + NEL;                // total 5*NEL*4 = 84.3 MB

    for (int L = 0; L < 2; ++L) {
        int shift = (L == 0) ? 0 : 3;
        const float* xin_l = (L == 0) ? x : buf_x;
        float* xmid = buf_x;
        float* xfin = (L == 0) ? buf_x : out;

        k_ln_part<<<TOK / 4, 256, 0, stream>>>(xin_l, n1g + L * 96, n1b + L * 96, buf_h, shift);
        k_qkv<<<TOK / 8, 256, 0, stream>>>(buf_h, qkvw + L * 288 * 96, qkvb + L * 288, bq, bk, bv);
        k_attn<<<NWIN * NHD, 256, 0, stream>>>(bq, bk, bv, relb + L * NBIAS * NHD, buf_h,
                                               shift ? 1 : 0);
        k_proj<<<TOK / 16, 256, 0, stream>>>(buf_h, projw + L * 96 * 96, projb + L * 96,
                                             xin_l, xmid, shift);
        k_mlp<<<TOK / 8, 256, 0, stream>>>(xmid, xfin, n2g + L * 96, n2b + L * 96,
                                           fc1w + L * 384 * 96, fc1b + L * 384,
                                           fc2w + L * 96 * 384, fc2b + L * 96);
    }
}

// Round 2
// 1382.121 us; speedup vs baseline: 1.3480x; 1.3480x over previous
//
#include <hip/hip_runtime.h>
#include <math.h>

#define DIM 96
#define NHD 3
#define HD 32
#define NWT 343          // tokens per window
#define NWIN 128         // b * windows
#define TOK 43904        // total tokens = 2*28^3
#define NBIAS 2197       // (2*7-1)^3
#define SCALE 0.17677669529663687f

__device__ __forceinline__ float waveReduceSum(float v) {
    #pragma unroll
    for (int off = 32; off > 0; off >>= 1) v += __shfl_xor(v, off, 64);
    return v;
}

__device__ __forceinline__ unsigned short f2b(float f) {
    union { float f; unsigned int u; } x; x.f = f;
    unsigned int r = (x.u + 0x7fffu + ((x.u >> 16) & 1u)) >> 16;
    return (unsigned short)r;
}
__device__ __forceinline__ float b2f(unsigned short h) {
    union { unsigned int u; float f; } x; x.u = ((unsigned int)h) << 16;
    return x.f;
}
__device__ __forceinline__ float lo16(unsigned int u) {
    union { unsigned int u; float f; } x; x.u = u << 16; return x.f;
}
__device__ __forceinline__ float hi16(unsigned int u) {
    union { unsigned int u; float f; } x; x.u = u & 0xffff0000u; return x.f;
}

// ---------------- K1: LN1 + roll(-shift) + window partition -----------------
__global__ void __launch_bounds__(256) k_ln_part(
        const float* __restrict__ x, const float* __restrict__ g,
        const float* __restrict__ bta, float* __restrict__ hw, int shift) {
    int wave = (blockIdx.x * blockDim.x + threadIdx.x) >> 6;
    int lane = threadIdx.x & 63;
    if (wave >= TOK) return;
    int bw = wave / NWT, n = wave % NWT;
    int b = bw >> 6, win = bw & 63;
    int wdi = win >> 4, whi = (win >> 2) & 3, wwi = win & 3;
    int d = n / 49, h = (n / 7) % 7, w = n % 7;
    int gd = wdi * 7 + d, gh = whi * 7 + h, gw = wwi * 7 + w;
    int sd = (gd + shift) % 28, sh = (gh + shift) % 28, sw = (gw + shift) % 28;
    const float* row = x + (((size_t)(b * 28 + sd) * 28 + sh) * 28 + sw) * DIM;
    float e0 = row[lane];
    float e1 = (lane < 32) ? row[64 + lane] : 0.0f;
    float s  = waveReduceSum(e0 + e1);
    float mu = s * (1.0f / 96.0f);
    float s2 = waveReduceSum(e0 * e0 + e1 * e1);
    float var = s2 * (1.0f / 96.0f) - mu * mu;
    float rstd = rsqrtf(var + 1e-5f);
    float* dst = hw + (size_t)wave * DIM;
    dst[lane] = (e0 - mu) * rstd * g[lane] + bta[lane];
    if (lane < 32) dst[64 + lane] = (e1 - mu) * rstd * g[64 + lane] + bta[64 + lane];
}

// ---------------- K2: QKV GEMM, 32 tokens/block, bf16 W^T in LDS ------------
#define QKV_TB 32
__global__ void __launch_bounds__(256) k_qkv(
        const float* __restrict__ hw, const float* __restrict__ W,
        const float* __restrict__ bias, float* __restrict__ q,
        float* __restrict__ k, float* __restrict__ v) {
    __shared__ unsigned short xs[QKV_TB * 96];     // 6144 B
    __shared__ unsigned short wT[96 * 288];        // 55296 B
    int base = blockIdx.x * QKV_TB;
    for (int i = threadIdx.x; i < QKV_TB * 96; i += 256)
        xs[i] = f2b(hw[(size_t)base * 96 + i]);
    for (int i = threadIdx.x; i < 288 * 96; i += 256) {
        int c = i / 96, kk = i % 96;
        wT[kk * 288 + c] = f2b(W[i]);
    }
    __syncthreads();
    int tg = threadIdx.x >> 5;        // 0..7, tokens tg*4..tg*4+3
    int cg = threadIdx.x & 31;        // col group, 8 cols each
    for (int cb = 0; cb < 2; ++cb) {
        int c0 = cb * 256 + cg * 8;
        if (c0 >= 288) break;
        float acc[4][8];
        #pragma unroll
        for (int t = 0; t < 4; ++t)
            #pragma unroll
            for (int cc = 0; cc < 8; ++cc) acc[t][cc] = 0.f;
        for (int kk = 0; kk < 96; kk += 2) {
            uint4 w0 = *((const uint4*)(wT + kk * 288 + c0));
            uint4 w1 = *((const uint4*)(wT + (kk + 1) * 288 + c0));
            float wf0[8], wf1[8];
            wf0[0]=lo16(w0.x); wf0[1]=hi16(w0.x); wf0[2]=lo16(w0.y); wf0[3]=hi16(w0.y);
            wf0[4]=lo16(w0.z); wf0[5]=hi16(w0.z); wf0[6]=lo16(w0.w); wf0[7]=hi16(w0.w);
            wf1[0]=lo16(w1.x); wf1[1]=hi16(w1.x); wf1[2]=lo16(w1.y); wf1[3]=hi16(w1.y);
            wf1[4]=lo16(w1.z); wf1[5]=hi16(w1.z); wf1[6]=lo16(w1.w); wf1[7]=hi16(w1.w);
            #pragma unroll
            for (int t = 0; t < 4; ++t) {
                unsigned int xp = *((const unsigned int*)(xs + (tg * 4 + t) * 96 + kk));
                float xl = lo16(xp), xh = hi16(xp);
                #pragma unroll
                for (int cc = 0; cc < 8; ++cc)
                    acc[t][cc] += xl * wf0[cc] + xh * wf1[cc];
            }
        }
        int which = c0 / 96, hdc = c0 % 96;
        int head = hdc >> 5, hd0 = hdc & 31;
        float sc = (which == 0) ? SCALE : 1.0f;
        float* dstp = (which == 0) ? q : (which == 1) ? k : v;
        #pragma unroll
        for (int t = 0; t < 4; ++t) {
            int tok = base + tg * 4 + t;
            int bw = tok / NWT, n = tok % NWT;
            float* dp = dstp + (((size_t)bw * NHD + head) * NWT + n) * HD + hd0;
            #pragma unroll
            for (int cc = 0; cc < 8; ++cc)
                dp[cc] = (acc[t][cc] + bias[c0 + cc]) * sc;
        }
    }
}

// ---------------- K3: attention, single-pass softmax, tiled K/V LDS ---------
#define ATT_T 384
#define JT 128
__global__ void __launch_bounds__(384) k_attn(
        const float* __restrict__ q, const float* __restrict__ k,
        const float* __restrict__ v, const float* __restrict__ rel,
        float* __restrict__ o, int shifted) {
    __shared__ float kt[JT * HD];    // 16384 B
    __shared__ float vt[JT * HD];    // 16384 B
    __shared__ float relh[NBIAS];    //  8788 B
    __shared__ int   jinfo[NWT];     //  1372 B
    int bw = blockIdx.x / NHD, head = blockIdx.x % NHD;
    size_t hb = ((size_t)bw * NHD + head) * NWT * HD;
    for (int i = threadIdx.x; i < NBIAS; i += ATT_T) relh[i] = rel[i * NHD + head];
    int win = bw & 63;
    int wdi = win >> 4, whi = (win >> 2) & 3, wwi = win & 3;
    for (int i = threadIdx.x; i < NWT; i += ATT_T) {
        int d = i / 49, h = (i / 7) % 7, w = i % 7;
        int gd = wdi * 7 + d, gh = whi * 7 + h, gw = wwi * 7 + w;
        int rd = (gd < 21) ? 0 : ((gd < 25) ? 1 : 2);
        int rh = (gh < 21) ? 0 : ((gh < 25) ? 1 : 2);
        int rw = (gw < 21) ? 0 : ((gw < 25) ? 1 : 2);
        jinfo[i] = (d * 169 + h * 13 + w) | ((rd * 9 + rh * 3 + rw) << 16);
    }
    int r = threadIdx.x;
    bool act = r < NWT;
    float qr[HD], acc[HD];
    float denom = 0.f;
    int rbase = 0, cr = 0;
    if (act) {
        const float* qp = q + hb + (size_t)r * HD;
        #pragma unroll
        for (int d2 = 0; d2 < HD; ++d2) { qr[d2] = qp[d2]; acc[d2] = 0.f; }
        int rd0 = r / 49, rh0 = (r / 7) % 7, rw0 = r % 7;
        rbase = (rd0 + 6) * 169 + (rh0 + 6) * 13 + (rw0 + 6);
        int gd = wdi * 7 + rd0, gh = whi * 7 + rh0, gw = wwi * 7 + rw0;
        cr = ((gd < 21) ? 0 : ((gd < 25) ? 1 : 2)) * 9
           + ((gh < 21) ? 0 : ((gh < 25) ? 1 : 2)) * 3
           + ((gw < 21) ? 0 : ((gw < 25) ? 1 : 2));
    }
    for (int j0 = 0; j0 < NWT; j0 += JT) {
        int jlen = min(JT, NWT - j0);
        __syncthreads();
        int nel = jlen * HD;
        for (int i = threadIdx.x; i < nel; i += ATT_T) {
            kt[i] = k[hb + (size_t)j0 * HD + i];
            vt[i] = v[hb + (size_t)j0 * HD + i];
        }
        __syncthreads();
        if (act) {
            for (int jj = 0; jj < jlen; ++jj) {
                int ji = jinfo[j0 + jj];
                float s = 0.f;
                #pragma unroll
                for (int d2 = 0; d2 < HD; ++d2) s += qr[d2] * kt[jj * HD + d2];
                s += relh[rbase - (ji & 0xffff)];
                if (shifted && ((ji >> 16) != cr)) s -= 100.0f;
                float p = __expf(s);
                denom += p;
                #pragma unroll
                for (int d2 = 0; d2 < HD; ++d2) acc[d2] += p * vt[jj * HD + d2];
            }
        }
    }
    if (act) {
        float inv = 1.0f / denom;
        float* op = o + ((size_t)(bw * NWT + r)) * DIM + head * HD;
        #pragma unroll
        for (int d2 = 0; d2 < HD; ++d2) op[d2] = acc[d2] * inv;
    }
}

// ---------------- K4: proj + window reverse + roll(+shift) + residual -------
#define PRJ_TB 64
__global__ void __launch_bounds__(192) k_proj(
        const float* __restrict__ ao, const float* __restrict__ W,
        const float* __restrict__ bias, const float* __restrict__ xin,
        float* __restrict__ xout, int shift) {
    __shared__ unsigned short as_[PRJ_TB * 96];   // 12288 B
    __shared__ unsigned short wT[96 * 96];        // 18432 B
    __shared__ int tsrc[PRJ_TB];
    int base = blockIdx.x * PRJ_TB;
    if (threadIdx.x < PRJ_TB) {
        int tok = base + threadIdx.x;
        int b = tok / 21952, rem = tok % 21952;
        int D = rem / 784, H = (rem / 28) % 28, Wc = rem % 28;
        int gd = (D - shift + 28) % 28, gh = (H - shift + 28) % 28, gw = (Wc - shift + 28) % 28;
        int win = ((gd / 7) * 4 + (gh / 7)) * 4 + (gw / 7);
        int n = ((gd % 7) * 7 + (gh % 7)) * 7 + (gw % 7);
        tsrc[threadIdx.x] = (b * 64 + win) * NWT + n;
    }
    __syncthreads();
    for (int i = threadIdx.x; i < PRJ_TB * 96; i += 192) {
        int t = i / 96, cc = i % 96;
        as_[i] = f2b(ao[(size_t)tsrc[t] * 96 + cc]);
    }
    for (int i = threadIdx.x; i < 96 * 96; i += 192) {
        int c = i / 96, kk = i % 96;
        wT[kk * 96 + c] = f2b(W[i]);
    }
    __syncthreads();
    int cg = threadIdx.x % 12;      // 12 col groups x 8 cols
    int tg = threadIdx.x / 12;      // 16 token groups x 4 tokens
    int c0 = cg * 8;
    float acc[4][8];
    #pragma unroll
    for (int t = 0; t < 4; ++t)
        #pragma unroll
        for (int cc = 0; cc < 8; ++cc) acc[t][cc] = 0.f;
    for (int kk = 0; kk < 96; kk += 2) {
        uint4 w0 = *((const uint4*)(wT + kk * 96 + c0));
        uint4 w1 = *((const uint4*)(wT + (kk + 1) * 96 + c0));
        float wf0[8], wf1[8];
        wf0[0]=lo16(w0.x); wf0[1]=hi16(w0.x); wf0[2]=lo16(w0.y); wf0[3]=hi16(w0.y);
        wf0[4]=lo16(w0.z); wf0[5]=hi16(w0.z); wf0[6]=lo16(w0.w); wf0[7]=hi16(w0.w);
        wf1[0]=lo16(w1.x); wf1[1]=hi16(w1.x); wf1[2]=lo16(w1.y); wf1[3]=hi16(w1.y);
        wf1[4]=lo16(w1.z); wf1[5]=hi16(w1.z); wf1[6]=lo16(w1.w); wf1[7]=hi16(w1.w);
        #pragma unroll
        for (int t = 0; t < 4; ++t) {
            unsigned int xp = *((const unsigned int*)(as_ + (tg * 4 + t) * 96 + kk));
            float xl = lo16(xp), xh = hi16(xp);
            #pragma unroll
            for (int cc = 0; cc < 8; ++cc)
                acc[t][cc] += xl * wf0[cc] + xh * wf1[cc];
        }
    }
    #pragma unroll
    for (int t = 0; t < 4; ++t) {
        int tok = base + tg * 4 + t;
        #pragma unroll
        for (int cc = 0; cc < 8; ++cc) {
            size_t off = (size_t)tok * 96 + c0 + cc;
            xout[off] = xin[off] + acc[t][cc] + bias[c0 + cc];
        }
    }
}

// ---------------- K5: LN2 + fc1 + GELU + fc2 + residual ---------------------
#define MLP_TB 32
__global__ void __launch_bounds__(192) k_mlp(
        const float* __restrict__ xin, float* __restrict__ xout,
        const float* __restrict__ g2, const float* __restrict__ b2,
        const float* __restrict__ w1, const float* __restrict__ bb1,
        const float* __restrict__ w2, const float* __restrict__ bb2) {
    __shared__ unsigned short ln[MLP_TB * 96];        //  6144 B
    __shared__ unsigned short wbuf[32 * 392];         // 25088 B (w1 tiles padded; w2 tiles use 128*96)
    __shared__ unsigned short hid[MLP_TB * 384];      // 24576 B
    int base = blockIdx.x * MLP_TB;
    int wid = threadIdx.x >> 6, lane = threadIdx.x & 63;
    // LN2 (wave per row)
    for (int row = wid; row < MLP_TB; row += 3) {
        const float* rp = xin + (size_t)(base + row) * 96;
        float e0 = rp[lane];
        float e1 = (lane < 32) ? rp[64 + lane] : 0.f;
        float s  = waveReduceSum(e0 + e1);
        float mu = s * (1.0f / 96.0f);
        float s2 = waveReduceSum(e0 * e0 + e1 * e1);
        float rstd = rsqrtf(s2 * (1.0f / 96.0f) - mu * mu + 1e-5f);
        ln[row * 96 + lane] = f2b((e0 - mu) * rstd * g2[lane] + b2[lane]);
        if (lane < 32)
            ln[row * 96 + 64 + lane] = f2b((e1 - mu) * rstd * g2[64 + lane] + b2[64 + lane]);
    }
    int tg = threadIdx.x / 48;   // 0..3, 8 tokens each
    int cg = threadIdx.x % 48;
    int c0 = cg * 8;             // fc1 col base
    float acc[8][8];
    #pragma unroll
    for (int t = 0; t < 8; ++t)
        #pragma unroll
        for (int cc = 0; cc < 8; ++cc) acc[t][cc] = 0.f;
    for (int s = 0; s < 3; ++s) {
        __syncthreads();
        // stage w1 tile: kk in [32s, 32s+32), layout wbuf[kkl*392 + c]
        for (int i = threadIdx.x; i < 32 * 384; i += 192) {
            int kkl = i & 31, c = i >> 5;
            wbuf[kkl * 392 + c] = f2b(w1[c * 96 + s * 32 + kkl]);
        }
        __syncthreads();
        for (int kkl = 0; kkl < 32; kkl += 2) {
            int kk = s * 32 + kkl;
            uint4 w0 = *((const uint4*)(wbuf + kkl * 392 + c0));
            uint4 w1v = *((const uint4*)(wbuf + (kkl + 1) * 392 + c0));
            float wf0[8], wf1[8];
            wf0[0]=lo16(w0.x); wf0[1]=hi16(w0.x); wf0[2]=lo16(w0.y); wf0[3]=hi16(w0.y);
            wf0[4]=lo16(w0.z); wf0[5]=hi16(w0.z); wf0[6]=lo16(w0.w); wf0[7]=hi16(w0.w);
            wf1[0]=lo16(w1v.x); wf1[1]=hi16(w1v.x); wf1[2]=lo16(w1v.y); wf1[3]=hi16(w1v.y);
            wf1[4]=lo16(w1v.z); wf1[5]=hi16(w1v.z); wf1[6]=lo16(w1v.w); wf1[7]=hi16(w1v.w);
            #pragma unroll
            for (int t = 0; t < 8; ++t) {
                unsigned int xp = *((const unsigned int*)(ln + (tg * 8 + t) * 96 + kk));
                float xl = lo16(xp), xh = hi16(xp);
                #pragma unroll
                for (int cc = 0; cc < 8; ++cc)
                    acc[t][cc] += xl * wf0[cc] + xh * wf1[cc];
            }
        }
    }
    // GELU + store hid
    #pragma unroll
    for (int cc = 0; cc < 8; ++cc) {
        float bb = bb1[c0 + cc];
        #pragma unroll
        for (int t = 0; t < 8; ++t) {
            float v2 = acc[t][cc] + bb;
            float ge = 0.5f * v2 * (1.0f + erff(v2 * 0.70710678118654752f));
            hid[(tg * 8 + t) * 384 + c0 + cc] = f2b(ge);
        }
    }
    // fc2: thread = tg(0..3, 8 tokens) x cg(0..47, 2 cols)
    int c20 = cg * 2;
    float a2[8][2];
    #pragma unroll
    for (int t = 0; t < 8; ++t) { a2[t][0] = 0.f; a2[t][1] = 0.f; }
    for (int s = 0; s < 3; ++s) {
        __syncthreads();
        // stage w2 tile: kk in [128s, 128s+128), layout wbuf[kkl*96 + c]
        for (int i = threadIdx.x; i < 128 * 96; i += 192) {
            int kkl = i & 127, c = i >> 7;
            wbuf[kkl * 96 + c] = f2b(w2[c * 384 + s * 128 + kkl]);
        }
        __syncthreads();
        for (int kkl = 0; kkl < 128; kkl += 2) {
            int kk = s * 128 + kkl;
            unsigned int wp0 = *((const unsigned int*)(wbuf + kkl * 96 + c20));
            unsigned int wp1 = *((const unsigned int*)(wbuf + (kkl + 1) * 96 + c20));
            float w00 = lo16(wp0), w01 = hi16(wp0);
            float w10 = lo16(wp1), w11 = hi16(wp1);
            #pragma unroll
            for (int t = 0; t < 8; ++t) {
                unsigned int hp = *((const unsigned int*)(hid + (tg * 8 + t) * 384 + kk));
                float hl = lo16(hp), hh = hi16(hp);
                a2[t][0] += hl * w00 + hh * w10;
                a2[t][1] += hl * w01 + hh * w11;
            }
        }
    }
    float bb0 = bb2[c20], bb1v = bb2[c20 + 1];
    #pragma unroll
    for (int t = 0; t < 8; ++t) {
        size_t off = (size_t)(base + tg * 8 + t) * 96 + c20;
        xout[off]     = xin[off]     + a2[t][0] + bb0;
        xout[off + 1] = xin[off + 1] + a2[t][1] + bb1v;
    }
}

extern "C" void kernel_launch(void* const* d_in, const int* in_sizes, int n_in,
                              void* d_out, int out_size, void* d_ws, size_t ws_size,
                              hipStream_t stream) {
    const float* x     = (const float*)d_in[0];
    const float* n1g   = (const float*)d_in[1];
    const float* n1b   = (const float*)d_in[2];
    const float* qkvw  = (const float*)d_in[3];
    const float* qkvb  = (const float*)d_in[4];
    const float* relb  = (const float*)d_in[5];
    const float* projw = (const float*)d_in[6];
    const float* projb = (const float*)d_in[7];
    const float* n2g   = (const float*)d_in[8];
    const float* n2b   = (const float*)d_in[9];
    const float* fc1w  = (const float*)d_in[10];
    const float* fc1b  = (const float*)d_in[11];
    const float* fc2w  = (const float*)d_in[12];
    const float* fc2b  = (const float*)d_in[13];
    float* out = (float*)d_out;

    const size_t NEL = (size_t)TOK * DIM;
    float* buf_x = (float*)d_ws;
    float* buf_h = buf_x + NEL;
    float* bq    = buf_h + NEL;
    float* bk    = bq + NEL;
    float* bv    = bk + NEL;

    for (int L = 0; L < 2; ++L) {
        int shift = (L == 0) ? 0 : 3;
        const float* xin_l = (L == 0) ? x : buf_x;
        float* xmid = buf_x;
        float* xfin = (L == 0) ? buf_x : out;

        k_ln_part<<<TOK / 4, 256, 0, stream>>>(xin_l, n1g + L * 96, n1b + L * 96, buf_h, shift);
        k_qkv<<<TOK / QKV_TB, 256, 0, stream>>>(buf_h, qkvw + L * 288 * 96, qkvb + L * 288,
                                                bq, bk, bv);
        k_attn<<<NWIN * NHD, ATT_T, 0, stream>>>(bq, bk, bv, relb + L * NBIAS * NHD, buf_h,
                                                 shift ? 1 : 0);
        k_proj<<<TOK / PRJ_TB, 192, 0, stream>>>(buf_h, projw + L * 96 * 96, projb + L * 96,
                                                 xin_l, xmid, shift);
        k_mlp<<<TOK / MLP_TB, 192, 0, stream>>>(xmid, xfin, n2g + L * 96, n2b + L * 96,
                                                fc1w + L * 384 * 96, fc1b + L * 384,
                                                fc2w + L * 96 * 384, fc2b + L * 96);
    }
}

// Round 3
// 806.549 us; speedup vs baseline: 2.3099x; 1.7136x over previous
//
#include <hip/hip_runtime.h>
#include <math.h>

#define DIM 96
#define NHD 3
#define HD 32
#define NWT 343          // tokens per window
#define NWIN 128         // b * windows
#define TOK 43904        // total tokens = 2*28^3
#define NBIAS 2197       // (2*7-1)^3
#define SCALE 0.17677669529663687f

typedef __attribute__((ext_vector_type(8))) short bf16x8;
typedef __attribute__((ext_vector_type(4))) float f32x4;

__device__ __forceinline__ float waveReduceSum(float v) {
    #pragma unroll
    for (int off = 32; off > 0; off >>= 1) v += __shfl_xor(v, off, 64);
    return v;
}

__device__ __forceinline__ unsigned short f2b(float f) {
    union { float f; unsigned int u; } x; x.f = f;
    unsigned int r = (x.u + 0x7fffu + ((x.u >> 16) & 1u)) >> 16;
    return (unsigned short)r;
}

// ---------------- K0: fp32 -> bf16 weight conversion ------------------------
__global__ void __launch_bounds__(256) k_cvt(const float* __restrict__ src,
                                             unsigned short* __restrict__ dst, int n) {
    int i = blockIdx.x * 256 + threadIdx.x;
    if (i < n) dst[i] = f2b(src[i]);
}

// ---------------- K1: LN1 + roll(-shift) + window partition -> bf16 ---------
__global__ void __launch_bounds__(256) k_ln_part(
        const float* __restrict__ x, const float* __restrict__ g,
        const float* __restrict__ bta, unsigned short* __restrict__ hw, int shift) {
    int wave = (blockIdx.x * blockDim.x + threadIdx.x) >> 6;
    int lane = threadIdx.x & 63;
    if (wave >= TOK) return;
    int bw = wave / NWT, n = wave % NWT;
    int b = bw >> 6, win = bw & 63;
    int wdi = win >> 4, whi = (win >> 2) & 3, wwi = win & 3;
    int d = n / 49, h = (n / 7) % 7, w = n % 7;
    int gd = wdi * 7 + d, gh = whi * 7 + h, gw = wwi * 7 + w;
    int sd = (gd + shift) % 28, sh = (gh + shift) % 28, sw = (gw + shift) % 28;
    const float* row = x + (((size_t)(b * 28 + sd) * 28 + sh) * 28 + sw) * DIM;
    float e0 = row[lane];
    float e1 = (lane < 32) ? row[64 + lane] : 0.0f;
    float s  = waveReduceSum(e0 + e1);
    float mu = s * (1.0f / 96.0f);
    float s2 = waveReduceSum(e0 * e0 + e1 * e1);
    float rstd = rsqrtf(s2 * (1.0f / 96.0f) - mu * mu + 1e-5f);
    unsigned short* dst = hw + (size_t)wave * DIM;
    dst[lane] = f2b((e0 - mu) * rstd * g[lane] + bta[lane]);
    if (lane < 32) dst[64 + lane] = f2b((e1 - mu) * rstd * g[64 + lane] + bta[64 + lane]);
}

// ---------------- K2: QKV MFMA GEMM [TOK x 96] @ [96 x 288]^T ---------------
__global__ void __launch_bounds__(256) k_qkv(
        const unsigned short* __restrict__ hw, const unsigned short* __restrict__ W,
        const float* __restrict__ bias, float* __restrict__ q,
        float* __restrict__ k, float* __restrict__ v) {
    int wid = threadIdx.x >> 6, lane = threadIdx.x & 63;
    int m0 = blockIdx.x * 64 + wid * 16;
    int lm = lane & 15, q4 = lane >> 4;
    f32x4 acc[18];
    #pragma unroll
    for (int c = 0; c < 18; ++c) acc[c] = (f32x4){0.f, 0.f, 0.f, 0.f};
    const unsigned short* arow = hw + (size_t)(m0 + lm) * 96;
    const unsigned short* brow = W + (size_t)lm * 96;
    #pragma unroll
    for (int ks = 0; ks < 3; ++ks) {
        bf16x8 a = *((const bf16x8*)(arow + ks * 32 + q4 * 8));
        const unsigned short* bp = brow + ks * 32 + q4 * 8;
        #pragma unroll
        for (int c = 0; c < 18; ++c) {
            bf16x8 b = *((const bf16x8*)(bp + c * 16 * 96));
            acc[c] = __builtin_amdgcn_mfma_f32_16x16x32_bf16(a, b, acc[c], 0, 0, 0);
        }
    }
    int bwr[4], nnr[4];
    #pragma unroll
    for (int r = 0; r < 4; ++r) {
        int tok = m0 + q4 * 4 + r;
        bwr[r] = tok / NWT; nnr[r] = tok % NWT;
    }
    #pragma unroll
    for (int c = 0; c < 18; ++c) {
        int n0 = c * 16;
        int which = n0 / 96;
        int hrem = n0 % 96;
        int head = (hrem + lm) >> 5;
        int hd = (hrem + lm) & 31;
        float* dstp = (which == 0) ? q : (which == 1) ? k : v;
        float sc = (which == 0) ? SCALE : 1.0f;
        float bb = bias[n0 + lm];
        #pragma unroll
        for (int r = 0; r < 4; ++r) {
            dstp[(((size_t)bwr[r] * NHD + head) * NWT + nnr[r]) * HD + hd] =
                (acc[c][r] + bb) * sc;
        }
    }
}

// ---------------- K3: attention (fp32 VALU, single-pass softmax) ------------
#define ATT_T 384
#define JT 128
__global__ void __launch_bounds__(384) k_attn(
        const float* __restrict__ q, const float* __restrict__ k,
        const float* __restrict__ v, const float* __restrict__ rel,
        unsigned short* __restrict__ o, int shifted) {
    __shared__ float kt[JT * HD];
    __shared__ float vt[JT * HD];
    __shared__ float relh[NBIAS];
    __shared__ int   jinfo[NWT];
    int bw = blockIdx.x / NHD, head = blockIdx.x % NHD;
    size_t hb = ((size_t)bw * NHD + head) * NWT * HD;
    for (int i = threadIdx.x; i < NBIAS; i += ATT_T) relh[i] = rel[i * NHD + head];
    int win = bw & 63;
    int wdi = win >> 4, whi = (win >> 2) & 3, wwi = win & 3;
    for (int i = threadIdx.x; i < NWT; i += ATT_T) {
        int d = i / 49, h = (i / 7) % 7, w = i % 7;
        int gd = wdi * 7 + d, gh = whi * 7 + h, gw = wwi * 7 + w;
        int rd = (gd < 21) ? 0 : ((gd < 25) ? 1 : 2);
        int rh = (gh < 21) ? 0 : ((gh < 25) ? 1 : 2);
        int rw = (gw < 21) ? 0 : ((gw < 25) ? 1 : 2);
        jinfo[i] = (d * 169 + h * 13 + w) | ((rd * 9 + rh * 3 + rw) << 16);
    }
    int r = threadIdx.x;
    bool act = r < NWT;
    float qr[HD], acc[HD];
    float denom = 0.f;
    int rbase = 0, cr = 0;
    if (act) {
        const float* qp = q + hb + (size_t)r * HD;
        #pragma unroll
        for (int d2 = 0; d2 < HD; ++d2) { qr[d2] = qp[d2]; acc[d2] = 0.f; }
        int rd0 = r / 49, rh0 = (r / 7) % 7, rw0 = r % 7;
        rbase = (rd0 + 6) * 169 + (rh0 + 6) * 13 + (rw0 + 6);
        int gd = wdi * 7 + rd0, gh = whi * 7 + rh0, gw = wwi * 7 + rw0;
        cr = ((gd < 21) ? 0 : ((gd < 25) ? 1 : 2)) * 9
           + ((gh < 21) ? 0 : ((gh < 25) ? 1 : 2)) * 3
           + ((gw < 21) ? 0 : ((gw < 25) ? 1 : 2));
    }
    for (int j0 = 0; j0 < NWT; j0 += JT) {
        int jlen = min(JT, NWT - j0);
        __syncthreads();
        int nel = jlen * HD;
        for (int i = threadIdx.x; i < nel; i += ATT_T) {
            kt[i] = k[hb + (size_t)j0 * HD + i];
            vt[i] = v[hb + (size_t)j0 * HD + i];
        }
        __syncthreads();
        if (act) {
            for (int jj = 0; jj < jlen; ++jj) {
                int ji = jinfo[j0 + jj];
                float s = 0.f;
                #pragma unroll
                for (int d2 = 0; d2 < HD; ++d2) s += qr[d2] * kt[jj * HD + d2];
                s += relh[rbase - (ji & 0xffff)];
                if (shifted && ((ji >> 16) != cr)) s -= 100.0f;
                float p = __expf(s);
                denom += p;
                #pragma unroll
                for (int d2 = 0; d2 < HD; ++d2) acc[d2] += p * vt[jj * HD + d2];
            }
        }
    }
    if (act) {
        float inv = 1.0f / denom;
        unsigned int pk[16];
        #pragma unroll
        for (int d2 = 0; d2 < 16; ++d2)
            pk[d2] = (unsigned int)f2b(acc[2 * d2] * inv)
                   | ((unsigned int)f2b(acc[2 * d2 + 1] * inv) << 16);
        uint4* op = (uint4*)(o + ((size_t)(bw * NWT + r)) * DIM + head * HD);
        op[0] = (uint4){pk[0], pk[1], pk[2], pk[3]};
        op[1] = (uint4){pk[4], pk[5], pk[6], pk[7]};
        op[2] = (uint4){pk[8], pk[9], pk[10], pk[11]};
        op[3] = (uint4){pk[12], pk[13], pk[14], pk[15]};
    }
}

// ---------------- K4: proj MFMA + window reverse + roll + residual ----------
__global__ void __launch_bounds__(256) k_proj(
        const unsigned short* __restrict__ ao, const unsigned short* __restrict__ W,
        const float* __restrict__ bias, const float* __restrict__ xin,
        float* __restrict__ xout, int shift) {
    int wid = threadIdx.x >> 6, lane = threadIdx.x & 63;
    int m0 = blockIdx.x * 64 + wid * 16;
    int lm = lane & 15, q4 = lane >> 4;
    f32x4 acc[6];
    #pragma unroll
    for (int c = 0; c < 6; ++c) acc[c] = (f32x4){0.f, 0.f, 0.f, 0.f};
    const unsigned short* arow = ao + (size_t)(m0 + lm) * 96;
    const unsigned short* brow = W + (size_t)lm * 96;
    #pragma unroll
    for (int ks = 0; ks < 3; ++ks) {
        bf16x8 a = *((const bf16x8*)(arow + ks * 32 + q4 * 8));
        const unsigned short* bp = brow + ks * 32 + q4 * 8;
        #pragma unroll
        for (int c = 0; c < 6; ++c) {
            bf16x8 b = *((const bf16x8*)(bp + c * 16 * 96));
            acc[c] = __builtin_amdgcn_mfma_f32_16x16x32_bf16(a, b, acc[c], 0, 0, 0);
        }
    }
    size_t rowoff[4];
    #pragma unroll
    for (int r = 0; r < 4; ++r) {
        int wtok = m0 + q4 * 4 + r;
        int bw = wtok / NWT, n = wtok % NWT;
        int b = bw >> 6, win = bw & 63;
        int wdi = win >> 4, whi = (win >> 2) & 3, wwi = win & 3;
        int d = n / 49, h = (n / 7) % 7, w = n % 7;
        int sd = (wdi * 7 + d + shift) % 28;
        int sh = (whi * 7 + h + shift) % 28;
        int sw = (wwi * 7 + w + shift) % 28;
        rowoff[r] = (((size_t)(b * 28 + sd) * 28 + sh) * 28 + sw) * 96;
    }
    #pragma unroll
    for (int c = 0; c < 6; ++c) {
        int n = c * 16 + lm;
        float bb = bias[n];
        #pragma unroll
        for (int r = 0; r < 4; ++r) {
            size_t off = rowoff[r] + n;
            xout[off] = xin[off] + acc[c][r] + bb;
        }
    }
}

// ---------------- K5: MLP MFMA: LN2 + fc1 + GELU + fc2 + residual -----------
__global__ void __launch_bounds__(256) k_mlp(
        const float* __restrict__ xin, float* __restrict__ xout,
        const float* __restrict__ g2, const float* __restrict__ b2,
        const unsigned short* __restrict__ w1, const float* __restrict__ bb1,
        const unsigned short* __restrict__ w2, const float* __restrict__ bb2) {
    __shared__ unsigned short ln[64 * 104];   // 13312 B, stride 104 -> 2-way banks
    __shared__ unsigned short hid[64 * 392];  // 50176 B, stride 392 -> 2-way banks
    int wid = threadIdx.x >> 6, lane = threadIdx.x & 63;
    int base = blockIdx.x * 64;
    // LN2: wave wid handles rows wid*16 .. wid*16+15
    #pragma unroll 2
    for (int i = 0; i < 16; ++i) {
        int row = wid * 16 + i;
        const float* rp = xin + (size_t)(base + row) * 96;
        float e0 = rp[lane];
        float e1 = (lane < 32) ? rp[64 + lane] : 0.f;
        float s  = waveReduceSum(e0 + e1);
        float mu = s * (1.0f / 96.0f);
        float s2 = waveReduceSum(e0 * e0 + e1 * e1);
        float rstd = rsqrtf(s2 * (1.0f / 96.0f) - mu * mu + 1e-5f);
        ln[row * 104 + lane] = f2b((e0 - mu) * rstd * g2[lane] + b2[lane]);
        if (lane < 32)
            ln[row * 104 + 64 + lane] = f2b((e1 - mu) * rstd * g2[64 + lane] + b2[64 + lane]);
    }
    __syncthreads();
    int lm = lane & 15, q4 = lane >> 4;
    int m = wid * 16 + lm;
    // fc1: 16 tokens x 384 cols per wave
    f32x4 acc[24];
    #pragma unroll
    for (int c = 0; c < 24; ++c) acc[c] = (f32x4){0.f, 0.f, 0.f, 0.f};
    #pragma unroll
    for (int ks = 0; ks < 3; ++ks) {
        bf16x8 a = *((const bf16x8*)(ln + m * 104 + ks * 32 + q4 * 8));
        const unsigned short* bp = w1 + (size_t)lm * 96 + ks * 32 + q4 * 8;
        #pragma unroll
        for (int c = 0; c < 24; ++c) {
            bf16x8 b = *((const bf16x8*)(bp + c * 16 * 96));
            acc[c] = __builtin_amdgcn_mfma_f32_16x16x32_bf16(a, b, acc[c], 0, 0, 0);
        }
    }
    // GELU -> hid (bf16)
    #pragma unroll
    for (int c = 0; c < 24; ++c) {
        int n = c * 16 + lm;
        float bb = bb1[n];
        #pragma unroll
        for (int r = 0; r < 4; ++r) {
            int row = wid * 16 + q4 * 4 + r;
            float v2 = acc[c][r] + bb;
            float ge = 0.5f * v2 * (1.0f + erff(v2 * 0.70710678118654752f));
            hid[row * 392 + n] = f2b(ge);
        }
    }
    __syncthreads();
    // fc2: 16 tokens x 96 cols per wave
    f32x4 a2[6];
    #pragma unroll
    for (int c = 0; c < 6; ++c) a2[c] = (f32x4){0.f, 0.f, 0.f, 0.f};
    #pragma unroll
    for (int ks = 0; ks < 12; ++ks) {
        bf16x8 a = *((const bf16x8*)(hid + m * 392 + ks * 32 + q4 * 8));
        const unsigned short* bp = w2 + (size_t)lm * 384 + ks * 32 + q4 * 8;
        #pragma unroll
        for (int c = 0; c < 6; ++c) {
            bf16x8 b = *((const bf16x8*)(bp + c * 16 * 384));
            a2[c] = __builtin_amdgcn_mfma_f32_16x16x32_bf16(a, b, a2[c], 0, 0, 0);
        }
    }
    #pragma unroll
    for (int c = 0; c < 6; ++c) {
        int n = c * 16 + lm;
        float bb = bb2[n];
        #pragma unroll
        for (int r = 0; r < 4; ++r) {
            size_t off = (size_t)(base + wid * 16 + q4 * 4 + r) * 96 + n;
            xout[off] = xin[off] + a2[c][r] + bb;
        }
    }
}

extern "C" void kernel_launch(void* const* d_in, const int* in_sizes, int n_in,
                              void* d_out, int out_size, void* d_ws, size_t ws_size,
                              hipStream_t stream) {
    const float* x     = (const float*)d_in[0];
    const float* n1g   = (const float*)d_in[1];
    const float* n1b   = (const float*)d_in[2];
    const float* qkvw  = (const float*)d_in[3];
    const float* qkvb  = (const float*)d_in[4];
    const float* relb  = (const float*)d_in[5];
    const float* projw = (const float*)d_in[6];
    const float* projb = (const float*)d_in[7];
    const float* n2g   = (const float*)d_in[8];
    const float* n2b   = (const float*)d_in[9];
    const float* fc1w  = (const float*)d_in[10];
    const float* fc1b  = (const float*)d_in[11];
    const float* fc2w  = (const float*)d_in[12];
    const float* fc2b  = (const float*)d_in[13];
    float* out = (float*)d_out;

    const size_t NEL = (size_t)TOK * DIM;
    float* buf_x = (float*)d_ws;
    float* bq    = buf_x + NEL;
    float* bk    = bq + NEL;
    float* bv    = bk + NEL;
    unsigned short* hbuf = (unsigned short*)(bv + NEL);   // LN1 out / attn out, bf16
    unsigned short* wts  = hbuf + NEL;                    // 221184 shorts of bf16 weights
    unsigned short* wq  = wts;                 // 2 x 27648
    unsigned short* wp  = wq + 2 * 27648;      // 2 x 9216
    unsigned short* w1  = wp + 2 * 9216;       // 2 x 36864
    unsigned short* w2  = w1 + 2 * 36864;      // 2 x 36864

    k_cvt<<<(2 * 27648 + 255) / 256, 256, 0, stream>>>(qkvw, wq, 2 * 27648);
    k_cvt<<<(2 * 9216  + 255) / 256, 256, 0, stream>>>(projw, wp, 2 * 9216);
    k_cvt<<<(2 * 36864 + 255) / 256, 256, 0, stream>>>(fc1w, w1, 2 * 36864);
    k_cvt<<<(2 * 36864 + 255) / 256, 256, 0, stream>>>(fc2w, w2, 2 * 36864);

    for (int L = 0; L < 2; ++L) {
        int shift = (L == 0) ? 0 : 3;
        const float* xin_l = (L == 0) ? x : buf_x;
        float* xmid = buf_x;
        float* xfin = (L == 0) ? buf_x : out;

        k_ln_part<<<TOK / 4, 256, 0, stream>>>(xin_l, n1g + L * 96, n1b + L * 96, hbuf, shift);
        k_qkv<<<TOK / 64, 256, 0, stream>>>(hbuf, wq + L * 27648, qkvb + L * 288, bq, bk, bv);
        k_attn<<<NWIN * NHD, ATT_T, 0, stream>>>(bq, bk, bv, relb + L * NBIAS * NHD, hbuf,
                                                 shift ? 1 : 0);
        k_proj<<<TOK / 64, 256, 0, stream>>>(hbuf, wp + L * 9216, projb + L * 96,
                                             xin_l, xmid, shift);
        k_mlp<<<TOK / 64, 256, 0, stream>>>(xmid, xfin, n2g + L * 96, n2b + L * 96,
                                            w1 + L * 36864, fc1b + L * 384,
                                            w2 + L * 36864, fc2b + L * 96);
    }
}

// Round 4
// 469.461 us; speedup vs baseline: 3.9685x; 1.7180x over previous
//
#include <hip/hip_runtime.h>
#include <math.h>

#define DIM 96
#define NHD 3
#define HD 32
#define NWT 343          // tokens per window
#define NWIN 128         // b * windows
#define TOK 43904        // total tokens = 2*28^3
#define NBIAS 2197       // (2*7-1)^3
#define SCALE 0.17677669529663687f
#define TPAD 352         // padded token count per window (22 tiles of 16)

typedef __attribute__((ext_vector_type(8))) short bf16x8;
typedef __attribute__((ext_vector_type(4))) float f32x4;

__device__ __forceinline__ float waveReduceSum(float v) {
    #pragma unroll
    for (int off = 32; off > 0; off >>= 1) v += __shfl_xor(v, off, 64);
    return v;
}

__device__ __forceinline__ unsigned short f2b(float f) {
    union { float f; unsigned int u; } x; x.f = f;
    unsigned int r = (x.u + 0x7fffu + ((x.u >> 16) & 1u)) >> 16;
    return (unsigned short)r;
}
__device__ __forceinline__ unsigned int pk2bf(float a, float b) {
    union { float f; unsigned int u; } x, y; x.f = a; y.f = b;
    return ((x.u + 0x8000u) >> 16) | ((y.u + 0x8000u) & 0xffff0000u);
}

// ---------------- K0: fp32 -> bf16 weight conversion ------------------------
__global__ void __launch_bounds__(256) k_cvt(const float* __restrict__ src,
                                             unsigned short* __restrict__ dst, int n) {
    int i = blockIdx.x * 256 + threadIdx.x;
    if (i < n) dst[i] = f2b(src[i]);
}

// ---------------- K1: LN1 + roll(-shift) + window partition -> bf16 ---------
__global__ void __launch_bounds__(256) k_ln_part(
        const float* __restrict__ x, const float* __restrict__ g,
        const float* __restrict__ bta, unsigned short* __restrict__ hw, int shift) {
    int wave = (blockIdx.x * blockDim.x + threadIdx.x) >> 6;
    int lane = threadIdx.x & 63;
    if (wave >= TOK) return;
    int bw = wave / NWT, n = wave % NWT;
    int b = bw >> 6, win = bw & 63;
    int wdi = win >> 4, whi = (win >> 2) & 3, wwi = win & 3;
    int d = n / 49, h = (n / 7) % 7, w = n % 7;
    int gd = wdi * 7 + d, gh = whi * 7 + h, gw = wwi * 7 + w;
    int sd = (gd + shift) % 28, sh = (gh + shift) % 28, sw = (gw + shift) % 28;
    const float* row = x + (((size_t)(b * 28 + sd) * 28 + sh) * 28 + sw) * DIM;
    float e0 = row[lane];
    float e1 = (lane < 32) ? row[64 + lane] : 0.0f;
    float s  = waveReduceSum(e0 + e1);
    float mu = s * (1.0f / 96.0f);
    float s2 = waveReduceSum(e0 * e0 + e1 * e1);
    float rstd = rsqrtf(s2 * (1.0f / 96.0f) - mu * mu + 1e-5f);
    unsigned short* dst = hw + (size_t)wave * DIM;
    dst[lane] = f2b((e0 - mu) * rstd * g[lane] + bta[lane]);
    if (lane < 32) dst[64 + lane] = f2b((e1 - mu) * rstd * g[64 + lane] + bta[64 + lane]);
}

// ---------------- K2: QKV MFMA GEMM -> bf16 q/k [wh][352][32], vT [wh][32][352]
__global__ void __launch_bounds__(256) k_qkv(
        const unsigned short* __restrict__ hw, const unsigned short* __restrict__ W,
        const float* __restrict__ bias, unsigned short* __restrict__ q,
        unsigned short* __restrict__ k, unsigned short* __restrict__ v) {
    int wid = threadIdx.x >> 6, lane = threadIdx.x & 63;
    int m0 = blockIdx.x * 64 + wid * 16;
    int lm = lane & 15, q4 = lane >> 4;
    f32x4 acc[18];
    #pragma unroll
    for (int c = 0; c < 18; ++c) acc[c] = (f32x4){0.f, 0.f, 0.f, 0.f};
    const unsigned short* arow = hw + (size_t)(m0 + lm) * 96;
    const unsigned short* brow = W + (size_t)lm * 96;
    #pragma unroll
    for (int ks = 0; ks < 3; ++ks) {
        bf16x8 a = *((const bf16x8*)(arow + ks * 32 + q4 * 8));
        const unsigned short* bp = brow + ks * 32 + q4 * 8;
        #pragma unroll
        for (int c = 0; c < 18; ++c) {
            bf16x8 b = *((const bf16x8*)(bp + c * 16 * 96));
            acc[c] = __builtin_amdgcn_mfma_f32_16x16x32_bf16(a, b, acc[c], 0, 0, 0);
        }
    }
    int bwr[4], nnr[4];
    #pragma unroll
    for (int r = 0; r < 4; ++r) {
        int tok = m0 + q4 * 4 + r;
        bwr[r] = tok / NWT; nnr[r] = tok % NWT;
    }
    #pragma unroll
    for (int c = 0; c < 18; ++c) {
        int n0 = c * 16;
        int which = n0 / 96;            // 0=q, 1=k, 2=v
        int col = (n0 % 96) + lm;       // 0..95
        int head = col >> 5, hd = col & 31;
        float bb = bias[n0 + lm];
        #pragma unroll
        for (int r = 0; r < 4; ++r) {
            int wh = bwr[r] * NHD + head;
            float val = acc[c][r] + bb;
            if (which == 0)
                q[(size_t)wh * (TPAD * 32) + nnr[r] * 32 + hd] = f2b(val * SCALE);
            else if (which == 1)
                k[(size_t)wh * (TPAD * 32) + nnr[r] * 32 + hd] = f2b(val);
            else
                v[(size_t)wh * (32 * TPAD) + hd * TPAD + nnr[r]] = f2b(val);
        }
    }
}

// ---------------- K3: MFMA flash attention ----------------------------------
// grid = NWIN*NHD*2; block = 256 (4 waves); each block: one (window,head), half the q-tiles
__global__ void __launch_bounds__(256) k_attn(
        const unsigned short* __restrict__ q, const unsigned short* __restrict__ k,
        const unsigned short* __restrict__ vT, const float* __restrict__ rel,
        unsigned short* __restrict__ o, int shifted) {
    __shared__ float relh[NBIAS];                       //  8788 B
    __shared__ int   jinfo[NWT];                        //  1372 B
    __shared__ __align__(16) unsigned short vts[32 * 360];   // 23040 B, stride 360 -> 2-way banks
    __shared__ __align__(16) unsigned short pbuf[4][16 * 40]; //  5120 B, stride 40 -> 2-way banks
    __shared__ float dnm[4][16];
    int wh = blockIdx.x >> 1, half = blockIdx.x & 1;
    int bw = wh / NHD, head = wh % NHD;
    // stage rel bias for this head
    for (int i = threadIdx.x; i < NBIAS; i += 256) relh[i] = rel[i * NHD + head];
    // stage V^T [32][352] -> [32][360]
    const unsigned int* vsrc = (const unsigned int*)(vT + (size_t)wh * 32 * TPAD);
    unsigned int* vdst = (unsigned int*)vts;
    for (int i = threadIdx.x; i < 32 * 176; i += 256) {
        int row = i / 176, cc = i - row * 176;
        vdst[row * 180 + cc] = vsrc[i];
    }
    // jinfo: packed jcode | region<<16
    int win = bw & 63;
    int wdi = win >> 4, whi = (win >> 2) & 3, wwi = win & 3;
    for (int i = threadIdx.x; i < NWT; i += 256) {
        int d = i / 49, h = (i / 7) % 7, w = i % 7;
        int gd = wdi * 7 + d, gh = whi * 7 + h, gw = wwi * 7 + w;
        int rd = (gd < 21) ? 0 : ((gd < 25) ? 1 : 2);
        int rh = (gh < 21) ? 0 : ((gh < 25) ? 1 : 2);
        int rw = (gw < 21) ? 0 : ((gw < 25) ? 1 : 2);
        jinfo[i] = (d * 169 + h * 13 + w) | ((rd * 9 + rh * 3 + rw) << 16);
    }
    __syncthreads();
    int wid = threadIdx.x >> 6, lane = threadIdx.x & 63;
    int lm = lane & 15, q4 = lane >> 4;
    const unsigned short* qbase = q + (size_t)wh * TPAD * 32;
    const unsigned short* kbase = k + (size_t)wh * TPAD * 32;
    unsigned short* pb = pbuf[wid];
    for (int qtl = wid; qtl < 11; qtl += 4) {
        int qt = half * 11 + qtl;
        int qtok = qt * 16 + lm;
        bf16x8 qf = *((const bf16x8*)(qbase + qtok * 32 + q4 * 8));
        int jq = jinfo[min(qtok, NWT - 1)];
        int jqc = (jq & 0xffff) + 1098;       // rbase - jcode_k = jcode_q - jcode_k + 1098
        int rq = jq >> 16;
        f32x4 acc0 = (f32x4){0.f, 0.f, 0.f, 0.f};
        f32x4 acc1 = (f32x4){0.f, 0.f, 0.f, 0.f};
        float denom = 0.f;
        for (int pr = 0; pr < 11; ++pr) {
            int kb0 = pr * 32;
            bf16x8 kf0 = *((const bf16x8*)(kbase + (kb0 + lm) * 32 + q4 * 8));
            bf16x8 kf1 = *((const bf16x8*)(kbase + (kb0 + 16 + lm) * 32 + q4 * 8));
            f32x4 z = (f32x4){0.f, 0.f, 0.f, 0.f};
            f32x4 s0 = __builtin_amdgcn_mfma_f32_16x16x32_bf16(kf0, qf, z, 0, 0, 0);
            f32x4 s1 = __builtin_amdgcn_mfma_f32_16x16x32_bf16(kf1, qf, z, 0, 0, 0);
            float p[8];
            #pragma unroll
            for (int t = 0; t < 2; ++t) {
                #pragma unroll
                for (int r = 0; r < 4; ++r) {
                    int key = kb0 + t * 16 + q4 * 4 + r;
                    int jk = jinfo[min(key, NWT - 1)];
                    float s = (t ? s1[r] : s0[r]) + relh[jqc - (jk & 0xffff)];
                    if (shifted && ((jk >> 16) != rq)) s -= 100.0f;
                    float pv = __expf(s);
                    pv = (key < NWT) ? pv : 0.0f;
                    p[t * 4 + r] = pv;
                    denom += pv;
                }
            }
            // pack P (C-layout) -> pbuf rows=query stride 40 -> A-layout
            #pragma unroll
            for (int t = 0; t < 2; ++t) {
                *((unsigned int*)(pb + lm * 40 + t * 16 + q4 * 4)) =
                    pk2bf(p[t * 4 + 0], p[t * 4 + 1]);
                *((unsigned int*)(pb + lm * 40 + t * 16 + q4 * 4 + 2)) =
                    pk2bf(p[t * 4 + 2], p[t * 4 + 3]);
            }
            bf16x8 pf = *((const bf16x8*)(pb + lm * 40 + q4 * 8));
            bf16x8 v0 = *((const bf16x8*)(vts + lm * 360 + kb0 + q4 * 8));
            bf16x8 v1 = *((const bf16x8*)(vts + (16 + lm) * 360 + kb0 + q4 * 8));
            acc0 = __builtin_amdgcn_mfma_f32_16x16x32_bf16(pf, v0, acc0, 0, 0, 0);
            acc1 = __builtin_amdgcn_mfma_f32_16x16x32_bf16(pf, v1, acc1, 0, 0, 0);
        }
        // reduce denom across the 4 quads (same query lm)
        denom += __shfl_xor(denom, 16, 64);
        denom += __shfl_xor(denom, 32, 64);
        if (lane < 16) dnm[wid][lm] = denom;
        #pragma unroll
        for (int r = 0; r < 4; ++r) {
            int qrow = qt * 16 + q4 * 4 + r;
            if (qrow < NWT) {
                float inv = 1.0f / dnm[wid][q4 * 4 + r];
                unsigned short* op = o + (size_t)(bw * NWT + qrow) * DIM + head * HD;
                op[lm]      = f2b(acc0[r] * inv);
                op[16 + lm] = f2b(acc1[r] * inv);
            }
        }
    }
}

// ---------------- K4: proj MFMA + window reverse + roll + residual ----------
__global__ void __launch_bounds__(256) k_proj(
        const unsigned short* __restrict__ ao, const unsigned short* __restrict__ W,
        const float* __restrict__ bias, const float* __restrict__ xin,
        float* __restrict__ xout, int shift) {
    int wid = threadIdx.x >> 6, lane = threadIdx.x & 63;
    int m0 = blockIdx.x * 64 + wid * 16;
    int lm = lane & 15, q4 = lane >> 4;
    f32x4 acc[6];
    #pragma unroll
    for (int c = 0; c < 6; ++c) acc[c] = (f32x4){0.f, 0.f, 0.f, 0.f};
    const unsigned short* arow = ao + (size_t)(m0 + lm) * 96;
    const unsigned short* brow = W + (size_t)lm * 96;
    #pragma unroll
    for (int ks = 0; ks < 3; ++ks) {
        bf16x8 a = *((const bf16x8*)(arow + ks * 32 + q4 * 8));
        const unsigned short* bp = brow + ks * 32 + q4 * 8;
        #pragma unroll
        for (int c = 0; c < 6; ++c) {
            bf16x8 b = *((const bf16x8*)(bp + c * 16 * 96));
            acc[c] = __builtin_amdgcn_mfma_f32_16x16x32_bf16(a, b, acc[c], 0, 0, 0);
        }
    }
    size_t rowoff[4];
    #pragma unroll
    for (int r = 0; r < 4; ++r) {
        int wtok = m0 + q4 * 4 + r;
        int bw = wtok / NWT, n = wtok % NWT;
        int b = bw >> 6, win = bw & 63;
        int wdi = win >> 4, whi = (win >> 2) & 3, wwi = win & 3;
        int d = n / 49, h = (n / 7) % 7, w = n % 7;
        int sd = (wdi * 7 + d + shift) % 28;
        int sh = (whi * 7 + h + shift) % 28;
        int sw = (wwi * 7 + w + shift) % 28;
        rowoff[r] = (((size_t)(b * 28 + sd) * 28 + sh) * 28 + sw) * 96;
    }
    #pragma unroll
    for (int c = 0; c < 6; ++c) {
        int n = c * 16 + lm;
        float bb = bias[n];
        #pragma unroll
        for (int r = 0; r < 4; ++r) {
            size_t off = rowoff[r] + n;
            xout[off] = xin[off] + acc[c][r] + bb;
        }
    }
}

// ---------------- K5: MLP MFMA: LN2 + fc1 + GELU + fc2 + residual -----------
__global__ void __launch_bounds__(256) k_mlp(
        const float* __restrict__ xin, float* __restrict__ xout,
        const float* __restrict__ g2, const float* __restrict__ b2,
        const unsigned short* __restrict__ w1, const float* __restrict__ bb1,
        const unsigned short* __restrict__ w2, const float* __restrict__ bb2) {
    __shared__ unsigned short ln[64 * 104];   // stride 104 -> 2-way banks
    __shared__ unsigned short hid[64 * 392];  // stride 392 -> 2-way banks
    int wid = threadIdx.x >> 6, lane = threadIdx.x & 63;
    int base = blockIdx.x * 64;
    #pragma unroll 2
    for (int i = 0; i < 16; ++i) {
        int row = wid * 16 + i;
        const float* rp = xin + (size_t)(base + row) * 96;
        float e0 = rp[lane];
        float e1 = (lane < 32) ? rp[64 + lane] : 0.f;
        float s  = waveReduceSum(e0 + e1);
        float mu = s * (1.0f / 96.0f);
        float s2 = waveReduceSum(e0 * e0 + e1 * e1);
        float rstd = rsqrtf(s2 * (1.0f / 96.0f) - mu * mu + 1e-5f);
        ln[row * 104 + lane] = f2b((e0 - mu) * rstd * g2[lane] + b2[lane]);
        if (lane < 32)
            ln[row * 104 + 64 + lane] = f2b((e1 - mu) * rstd * g2[64 + lane] + b2[64 + lane]);
    }
    __syncthreads();
    int lm = lane & 15, q4 = lane >> 4;
    int m = wid * 16 + lm;
    f32x4 acc[24];
    #pragma unroll
    for (int c = 0; c < 24; ++c) acc[c] = (f32x4){0.f, 0.f, 0.f, 0.f};
    #pragma unroll
    for (int ks = 0; ks < 3; ++ks) {
        bf16x8 a = *((const bf16x8*)(ln + m * 104 + ks * 32 + q4 * 8));
        const unsigned short* bp = w1 + (size_t)lm * 96 + ks * 32 + q4 * 8;
        #pragma unroll
        for (int c = 0; c < 24; ++c) {
            bf16x8 b = *((const bf16x8*)(bp + c * 16 * 96));
            acc[c] = __builtin_amdgcn_mfma_f32_16x16x32_bf16(a, b, acc[c], 0, 0, 0);
        }
    }
    #pragma unroll
    for (int c = 0; c < 24; ++c) {
        int n = c * 16 + lm;
        float bb = bb1[n];
        #pragma unroll
        for (int r = 0; r < 4; ++r) {
            int row = wid * 16 + q4 * 4 + r;
            float v2 = acc[c][r] + bb;
            float ge = 0.5f * v2 * (1.0f + erff(v2 * 0.70710678118654752f));
            hid[row * 392 + n] = f2b(ge);
        }
    }
    __syncthreads();
    f32x4 a2[6];
    #pragma unroll
    for (int c = 0; c < 6; ++c) a2[c] = (f32x4){0.f, 0.f, 0.f, 0.f};
    #pragma unroll
    for (int ks = 0; ks < 12; ++ks) {
        bf16x8 a = *((const bf16x8*)(hid + m * 392 + ks * 32 + q4 * 8));
        const unsigned short* bp = w2 + (size_t)lm * 384 + ks * 32 + q4 * 8;
        #pragma unroll
        for (int c = 0; c < 6; ++c) {
            bf16x8 b = *((const bf16x8*)(bp + c * 16 * 384));
            a2[c] = __builtin_amdgcn_mfma_f32_16x16x32_bf16(a, b, a2[c], 0, 0, 0);
        }
    }
    #pragma unroll
    for (int c = 0; c < 6; ++c) {
        int n = c * 16 + lm;
        float bb = bb2[n];
        #pragma unroll
        for (int r = 0; r < 4; ++r) {
            size_t off = (size_t)(base + wid * 16 + q4 * 4 + r) * 96 + n;
            xout[off] = xin[off] + a2[c][r] + bb;
        }
    }
}

extern "C" void kernel_launch(void* const* d_in, const int* in_sizes, int n_in,
                              void* d_out, int out_size, void* d_ws, size_t ws_size,
                              hipStream_t stream) {
    const float* x     = (const float*)d_in[0];
    const float* n1g   = (const float*)d_in[1];
    const float* n1b   = (const float*)d_in[2];
    const float* qkvw  = (const float*)d_in[3];
    const float* qkvb  = (const float*)d_in[4];
    const float* relb  = (const float*)d_in[5];
    const float* projw = (const float*)d_in[6];
    const float* projb = (const float*)d_in[7];
    const float* n2g   = (const float*)d_in[8];
    const float* n2b   = (const float*)d_in[9];
    const float* fc1w  = (const float*)d_in[10];
    const float* fc1b  = (const float*)d_in[11];
    const float* fc2w  = (const float*)d_in[12];
    const float* fc2b  = (const float*)d_in[13];
    float* out = (float*)d_out;

    const size_t NEL = (size_t)TOK * DIM;
    const size_t QKN = (size_t)NWIN * NHD * TPAD * 32;   // 4,325,376 shorts per buffer
    float* buf_x = (float*)d_ws;
    unsigned short* hbuf = (unsigned short*)(buf_x + NEL);  // LN1 out / attn out, bf16 [tok][96]
    unsigned short* bq   = hbuf + NEL;       // [wh][352][32]
    unsigned short* bk   = bq + QKN;         // [wh][352][32]
    unsigned short* bv   = bk + QKN;         // [wh][32][352]  (V^T)
    unsigned short* wts  = bv + QKN;
    unsigned short* wq  = wts;                 // 2 x 27648
    unsigned short* wp  = wq + 2 * 27648;      // 2 x 9216
    unsigned short* w1  = wp + 2 * 9216;       // 2 x 36864
    unsigned short* w2  = w1 + 2 * 36864;      // 2 x 36864

    k_cvt<<<(2 * 27648 + 255) / 256, 256, 0, stream>>>(qkvw, wq, 2 * 27648);
    k_cvt<<<(2 * 9216  + 255) / 256, 256, 0, stream>>>(projw, wp, 2 * 9216);
    k_cvt<<<(2 * 36864 + 255) / 256, 256, 0, stream>>>(fc1w, w1, 2 * 36864);
    k_cvt<<<(2 * 36864 + 255) / 256, 256, 0, stream>>>(fc2w, w2, 2 * 36864);

    for (int L = 0; L < 2; ++L) {
        int shift = (L == 0) ? 0 : 3;
        const float* xin_l = (L == 0) ? x : buf_x;
        float* xmid = buf_x;
        float* xfin = (L == 0) ? buf_x : out;

        k_ln_part<<<TOK / 4, 256, 0, stream>>>(xin_l, n1g + L * 96, n1b + L * 96, hbuf, shift);
        k_qkv<<<TOK / 64, 256, 0, stream>>>(hbuf, wq + L * 27648, qkvb + L * 288, bq, bk, bv);
        k_attn<<<NWIN * NHD * 2, 256, 0, stream>>>(bq, bk, bv, relb + L * NBIAS * NHD, hbuf,
                                                   shift ? 1 : 0);
        k_proj<<<TOK / 64, 256, 0, stream>>>(hbuf, wp + L * 9216, projb + L * 96,
                                             xin_l, xmid, shift);
        k_mlp<<<TOK / 64, 256, 0, stream>>>(xmid, xfin, n2g + L * 96, n2b + L * 96,
                                            w1 + L * 36864, fc1b + L * 384,
                                            w2 + L * 36864, fc2b + L * 96);
    }
}

// Round 5
// 437.290 us; speedup vs baseline: 4.2604x; 1.0736x over previous
//
#include <hip/hip_runtime.h>
#include <math.h>

#define DIM 96
#define NHD 3
#define HD 32
#define NWT 343          // tokens per window
#define NWIN 128         // b * windows
#define TOK 43904        // total tokens = 2*28^3
#define NBIAS 2197       // (2*7-1)^3
#define SCALE 0.17677669529663687f
#define TPAD 352         // padded token count per window (22 tiles of 16)

typedef __attribute__((ext_vector_type(8))) short bf16x8;
typedef __attribute__((ext_vector_type(4))) float f32x4;

__device__ __forceinline__ float waveReduceSum(float v) {
    #pragma unroll
    for (int off = 32; off > 0; off >>= 1) v += __shfl_xor(v, off, 64);
    return v;
}

__device__ __forceinline__ unsigned short f2b(float f) {
    union { float f; unsigned int u; } x; x.f = f;
    unsigned int r = (x.u + 0x7fffu + ((x.u >> 16) & 1u)) >> 16;
    return (unsigned short)r;
}
__device__ __forceinline__ unsigned int pk2bf(float a, float b) {
    union { float f; unsigned int u; } x, y; x.f = a; y.f = b;
    return ((x.u + 0x8000u) >> 16) | ((y.u + 0x8000u) & 0xffff0000u);
}

// ---------------- K0: fp32 -> bf16 weight conversion ------------------------
__global__ void __launch_bounds__(256) k_cvt(const float* __restrict__ src,
                                             unsigned short* __restrict__ dst, int n) {
    int i = blockIdx.x * 256 + threadIdx.x;
    if (i < n) dst[i] = f2b(src[i]);
}

// ---------------- K1: LN1 + roll(-shift) + window partition -> bf16 ---------
__global__ void __launch_bounds__(256) k_ln_part(
        const float* __restrict__ x, const float* __restrict__ g,
        const float* __restrict__ bta, unsigned short* __restrict__ hw, int shift) {
    int wave = (blockIdx.x * blockDim.x + threadIdx.x) >> 6;
    int lane = threadIdx.x & 63;
    if (wave >= TOK) return;
    int bw = wave / NWT, n = wave % NWT;
    int b = bw >> 6, win = bw & 63;
    int wdi = win >> 4, whi = (win >> 2) & 3, wwi = win & 3;
    int d = n / 49, h = (n / 7) % 7, w = n % 7;
    int gd = wdi * 7 + d, gh = whi * 7 + h, gw = wwi * 7 + w;
    int sd = (gd + shift) % 28, sh = (gh + shift) % 28, sw = (gw + shift) % 28;
    const float* row = x + (((size_t)(b * 28 + sd) * 28 + sh) * 28 + sw) * DIM;
    float e0 = row[lane];
    float e1 = (lane < 32) ? row[64 + lane] : 0.0f;
    float s  = waveReduceSum(e0 + e1);
    float mu = s * (1.0f / 96.0f);
    float s2 = waveReduceSum(e0 * e0 + e1 * e1);
    float rstd = rsqrtf(s2 * (1.0f / 96.0f) - mu * mu + 1e-5f);
    unsigned short* dst = hw + (size_t)wave * DIM;
    dst[lane] = f2b((e0 - mu) * rstd * g[lane] + bta[lane]);
    if (lane < 32) dst[64 + lane] = f2b((e1 - mu) * rstd * g[64 + lane] + bta[64 + lane]);
}

// ---------------- K2: QKV MFMA GEMM -> bf16 q/k [wh][352][32], vT [wh][32][352]
__global__ void __launch_bounds__(256) k_qkv(
        const unsigned short* __restrict__ hw, const unsigned short* __restrict__ W,
        const float* __restrict__ bias, unsigned short* __restrict__ q,
        unsigned short* __restrict__ k, unsigned short* __restrict__ v) {
    int wid = threadIdx.x >> 6, lane = threadIdx.x & 63;
    int m0 = blockIdx.x * 64 + wid * 16;
    int lm = lane & 15, q4 = lane >> 4;
    f32x4 acc[18];
    #pragma unroll
    for (int c = 0; c < 18; ++c) acc[c] = (f32x4){0.f, 0.f, 0.f, 0.f};
    const unsigned short* arow = hw + (size_t)(m0 + lm) * 96;
    const unsigned short* brow = W + (size_t)lm * 96;
    #pragma unroll
    for (int ks = 0; ks < 3; ++ks) {
        bf16x8 a = *((const bf16x8*)(arow + ks * 32 + q4 * 8));
        const unsigned short* bp = brow + ks * 32 + q4 * 8;
        #pragma unroll
        for (int c = 0; c < 18; ++c) {
            bf16x8 b = *((const bf16x8*)(bp + c * 16 * 96));
            acc[c] = __builtin_amdgcn_mfma_f32_16x16x32_bf16(a, b, acc[c], 0, 0, 0);
        }
    }
    int bwr[4], nnr[4];
    #pragma unroll
    for (int r = 0; r < 4; ++r) {
        int tok = m0 + q4 * 4 + r;
        bwr[r] = tok / NWT; nnr[r] = tok % NWT;
    }
    #pragma unroll
    for (int c = 0; c < 18; ++c) {
        int n0 = c * 16;
        int which = n0 / 96;            // 0=q, 1=k, 2=v
        int col = (n0 % 96) + lm;       // 0..95
        int head = col >> 5, hd = col & 31;
        float bb = bias[n0 + lm];
        #pragma unroll
        for (int r = 0; r < 4; ++r) {
            int wh = bwr[r] * NHD + head;
            float val = acc[c][r] + bb;
            if (which == 0)
                q[(size_t)wh * (TPAD * 32) + nnr[r] * 32 + hd] = f2b(val * SCALE);
            else if (which == 1)
                k[(size_t)wh * (TPAD * 32) + nnr[r] * 32 + hd] = f2b(val);
            else
                v[(size_t)wh * (32 * TPAD) + hd * TPAD + nnr[r]] = f2b(val);
        }
    }
}

// ---------------- K3: MFMA flash attention ----------------------------------
__global__ void __launch_bounds__(256) k_attn(
        const unsigned short* __restrict__ q, const unsigned short* __restrict__ k,
        const unsigned short* __restrict__ vT, const float* __restrict__ rel,
        unsigned short* __restrict__ o, int shifted) {
    __shared__ float relh[NBIAS];
    __shared__ int   jinfo[NWT];
    __shared__ __align__(16) unsigned short vts[32 * 360];
    __shared__ __align__(16) unsigned short pbuf[4][16 * 40];
    __shared__ float dnm[4][16];
    int wh = blockIdx.x >> 1, half = blockIdx.x & 1;
    int bw = wh / NHD, head = wh % NHD;
    for (int i = threadIdx.x; i < NBIAS; i += 256) relh[i] = rel[i * NHD + head];
    const unsigned int* vsrc = (const unsigned int*)(vT + (size_t)wh * 32 * TPAD);
    unsigned int* vdst = (unsigned int*)vts;
    for (int i = threadIdx.x; i < 32 * 176; i += 256) {
        int row = i / 176, cc = i - row * 176;
        vdst[row * 180 + cc] = vsrc[i];
    }
    int win = bw & 63;
    int wdi = win >> 4, whi = (win >> 2) & 3, wwi = win & 3;
    for (int i = threadIdx.x; i < NWT; i += 256) {
        int d = i / 49, h = (i / 7) % 7, w = i % 7;
        int gd = wdi * 7 + d, gh = whi * 7 + h, gw = wwi * 7 + w;
        int rd = (gd < 21) ? 0 : ((gd < 25) ? 1 : 2);
        int rh = (gh < 21) ? 0 : ((gh < 25) ? 1 : 2);
        int rw = (gw < 21) ? 0 : ((gw < 25) ? 1 : 2);
        jinfo[i] = (d * 169 + h * 13 + w) | ((rd * 9 + rh * 3 + rw) << 16);
    }
    __syncthreads();
    int wid = threadIdx.x >> 6, lane = threadIdx.x & 63;
    int lm = lane & 15, q4 = lane >> 4;
    const unsigned short* qbase = q + (size_t)wh * TPAD * 32;
    const unsigned short* kbase = k + (size_t)wh * TPAD * 32;
    unsigned short* pb = pbuf[wid];
    for (int qtl = wid; qtl < 11; qtl += 4) {
        int qt = half * 11 + qtl;
        int qtok = qt * 16 + lm;
        bf16x8 qf = *((const bf16x8*)(qbase + qtok * 32 + q4 * 8));
        int jq = jinfo[min(qtok, NWT - 1)];
        int jqc = (jq & 0xffff) + 1098;
        int rq = jq >> 16;
        f32x4 acc0 = (f32x4){0.f, 0.f, 0.f, 0.f};
        f32x4 acc1 = (f32x4){0.f, 0.f, 0.f, 0.f};
        float denom = 0.f;
        for (int pr = 0; pr < 11; ++pr) {
            int kb0 = pr * 32;
            bf16x8 kf0 = *((const bf16x8*)(kbase + (kb0 + lm) * 32 + q4 * 8));
            bf16x8 kf1 = *((const bf16x8*)(kbase + (kb0 + 16 + lm) * 32 + q4 * 8));
            f32x4 z = (f32x4){0.f, 0.f, 0.f, 0.f};
            f32x4 s0 = __builtin_amdgcn_mfma_f32_16x16x32_bf16(kf0, qf, z, 0, 0, 0);
            f32x4 s1 = __builtin_amdgcn_mfma_f32_16x16x32_bf16(kf1, qf, z, 0, 0, 0);
            float p[8];
            #pragma unroll
            for (int t = 0; t < 2; ++t) {
                #pragma unroll
                for (int r = 0; r < 4; ++r) {
                    int key = kb0 + t * 16 + q4 * 4 + r;
                    int jk = jinfo[min(key, NWT - 1)];
                    float s = (t ? s1[r] : s0[r]) + relh[jqc - (jk & 0xffff)];
                    if (shifted && ((jk >> 16) != rq)) s -= 100.0f;
                    float pv = __expf(s);
                    pv = (key < NWT) ? pv : 0.0f;
                    p[t * 4 + r] = pv;
                    denom += pv;
                }
            }
            #pragma unroll
            for (int t = 0; t < 2; ++t) {
                *((unsigned int*)(pb + lm * 40 + t * 16 + q4 * 4)) =
                    pk2bf(p[t * 4 + 0], p[t * 4 + 1]);
                *((unsigned int*)(pb + lm * 40 + t * 16 + q4 * 4 + 2)) =
                    pk2bf(p[t * 4 + 2], p[t * 4 + 3]);
            }
            bf16x8 pf = *((const bf16x8*)(pb + lm * 40 + q4 * 8));
            bf16x8 v0 = *((const bf16x8*)(vts + lm * 360 + kb0 + q4 * 8));
            bf16x8 v1 = *((const bf16x8*)(vts + (16 + lm) * 360 + kb0 + q4 * 8));
            acc0 = __builtin_amdgcn_mfma_f32_16x16x32_bf16(pf, v0, acc0, 0, 0, 0);
            acc1 = __builtin_amdgcn_mfma_f32_16x16x32_bf16(pf, v1, acc1, 0, 0, 0);
        }
        denom += __shfl_xor(denom, 16, 64);
        denom += __shfl_xor(denom, 32, 64);
        if (lane < 16) dnm[wid][lm] = denom;
        #pragma unroll
        for (int r = 0; r < 4; ++r) {
            int qrow = qt * 16 + q4 * 4 + r;
            if (qrow < NWT) {
                float inv = 1.0f / dnm[wid][q4 * 4 + r];
                unsigned short* op = o + (size_t)(bw * NWT + qrow) * DIM + head * HD;
                op[lm]      = f2b(acc0[r] * inv);
                op[16 + lm] = f2b(acc1[r] * inv);
            }
        }
    }
}

// ---------------- K4: proj MFMA + reverse/roll + residual + LN2 -> bf16 -----
__global__ void __launch_bounds__(256) k_proj(
        const unsigned short* __restrict__ ao, const unsigned short* __restrict__ W,
        const float* __restrict__ bias, const float* __restrict__ xin,
        float* __restrict__ xout, unsigned short* __restrict__ lnb,
        const float* __restrict__ g2, const float* __restrict__ b2, int shift) {
    int wid = threadIdx.x >> 6, lane = threadIdx.x & 63;
    int m0 = blockIdx.x * 64 + wid * 16;
    int lm = lane & 15, q4 = lane >> 4;
    f32x4 acc[6];
    #pragma unroll
    for (int c = 0; c < 6; ++c) acc[c] = (f32x4){0.f, 0.f, 0.f, 0.f};
    const unsigned short* arow = ao + (size_t)(m0 + lm) * 96;
    const unsigned short* brow = W + (size_t)lm * 96;
    #pragma unroll
    for (int ks = 0; ks < 3; ++ks) {
        bf16x8 a = *((const bf16x8*)(arow + ks * 32 + q4 * 8));
        const unsigned short* bp = brow + ks * 32 + q4 * 8;
        #pragma unroll
        for (int c = 0; c < 6; ++c) {
            bf16x8 b = *((const bf16x8*)(bp + c * 16 * 96));
            acc[c] = __builtin_amdgcn_mfma_f32_16x16x32_bf16(a, b, acc[c], 0, 0, 0);
        }
    }
    size_t rowoff[4];
    #pragma unroll
    for (int r = 0; r < 4; ++r) {
        int wtok = m0 + q4 * 4 + r;
        int bw = wtok / NWT, n = wtok % NWT;
        int b = bw >> 6, win = bw & 63;
        int wdi = win >> 4, whi = (win >> 2) & 3, wwi = win & 3;
        int d = n / 49, h = (n / 7) % 7, w = n % 7;
        int sd = (wdi * 7 + d + shift) % 28;
        int sh = (whi * 7 + h + shift) % 28;
        int sw = (wwi * 7 + w + shift) % 28;
        rowoff[r] = (((size_t)(b * 28 + sd) * 28 + sh) * 28 + sw) * 96;
    }
    float val[6][4];
    float g2v[6], b2v[6];
    #pragma unroll
    for (int c = 0; c < 6; ++c) {
        int n = c * 16 + lm;
        float bb = bias[n];
        g2v[c] = g2[n]; b2v[c] = b2[n];
        #pragma unroll
        for (int r = 0; r < 4; ++r) {
            size_t off = rowoff[r] + n;
            float y = xin[off] + acc[c][r] + bb;
            val[c][r] = y;
            xout[off] = y;
        }
    }
    // LN2 over the 16-lane quad group (cols c*16+lm)
    #pragma unroll
    for (int r = 0; r < 4; ++r) {
        float s = 0.f, s2 = 0.f;
        #pragma unroll
        for (int c = 0; c < 6; ++c) { s += val[c][r]; s2 += val[c][r] * val[c][r]; }
        #pragma unroll
        for (int off = 8; off > 0; off >>= 1) {
            s  += __shfl_xor(s,  off, 64);
            s2 += __shfl_xor(s2, off, 64);
        }
        float mu = s * (1.0f / 96.0f);
        float rstd = rsqrtf(s2 * (1.0f / 96.0f) - mu * mu + 1e-5f);
        #pragma unroll
        for (int c = 0; c < 6; ++c) {
            lnb[rowoff[r] + c * 16 + lm] =
                f2b((val[c][r] - mu) * rstd * g2v[c] + b2v[c]);
        }
    }
}

// ---------------- K5: MLP MFMA, barrier-free: fc1 + GELU + fc2 + residual ---
__global__ void __launch_bounds__(256) k_mlp(
        const unsigned short* __restrict__ lnb, const float* __restrict__ xmid,
        float* __restrict__ xout,
        const unsigned short* __restrict__ w1, const float* __restrict__ bb1,
        const unsigned short* __restrict__ w2, const float* __restrict__ bb2) {
    __shared__ __align__(16) unsigned short hid[4][16 * 392 + 8];  // per-wave tile, no barriers
    int wid = threadIdx.x >> 6, lane = threadIdx.x & 63;
    int lm = lane & 15, q4 = lane >> 4;
    int m0 = blockIdx.x * 64 + wid * 16;
    unsigned short* hw_ = hid[wid];
    // fc1: [16 x 96] @ [96 x 384]^T
    f32x4 acc[24];
    #pragma unroll
    for (int c = 0; c < 24; ++c) acc[c] = (f32x4){0.f, 0.f, 0.f, 0.f};
    const unsigned short* arow = lnb + (size_t)(m0 + lm) * 96;
    const unsigned short* brow = w1 + (size_t)lm * 96;
    #pragma unroll
    for (int ks = 0; ks < 3; ++ks) {
        bf16x8 a = *((const bf16x8*)(arow + ks * 32 + q4 * 8));
        const unsigned short* bp = brow + ks * 32 + q4 * 8;
        #pragma unroll
        for (int c = 0; c < 24; ++c) {
            bf16x8 b = *((const bf16x8*)(bp + c * 16 * 96));
            acc[c] = __builtin_amdgcn_mfma_f32_16x16x32_bf16(a, b, acc[c], 0, 0, 0);
        }
    }
    // GELU -> per-wave hid tile (row = token-in-16, col = hidden)
    #pragma unroll
    for (int c = 0; c < 24; ++c) {
        int n = c * 16 + lm;
        float bb = bb1[n];
        #pragma unroll
        for (int r = 0; r < 4; ++r) {
            float v2 = acc[c][r] + bb;
            float ge = 0.5f * v2 * (1.0f + erff(v2 * 0.70710678118654752f));
            hw_[(q4 * 4 + r) * 392 + n] = f2b(ge);
        }
    }
    // fc2: [16 x 384] @ [384 x 96]^T   (same-wave LDS read, lgkmcnt only)
    f32x4 a2[6];
    #pragma unroll
    for (int c = 0; c < 6; ++c) a2[c] = (f32x4){0.f, 0.f, 0.f, 0.f};
    const unsigned short* brow2 = w2 + (size_t)lm * 384;
    #pragma unroll
    for (int ks = 0; ks < 12; ++ks) {
        bf16x8 a = *((const bf16x8*)(hw_ + lm * 392 + ks * 32 + q4 * 8));
        const unsigned short* bp = brow2 + ks * 32 + q4 * 8;
        #pragma unroll
        for (int c = 0; c < 6; ++c) {
            bf16x8 b = *((const bf16x8*)(bp + c * 16 * 384));
            a2[c] = __builtin_amdgcn_mfma_f32_16x16x32_bf16(a, b, a2[c], 0, 0, 0);
        }
    }
    #pragma unroll
    for (int c = 0; c < 6; ++c) {
        int n = c * 16 + lm;
        float bb = bb2[n];
        #pragma unroll
        for (int r = 0; r < 4; ++r) {
            size_t off = (size_t)(m0 + q4 * 4 + r) * 96 + n;
            xout[off] = xmid[off] + a2[c][r] + bb;
        }
    }
}

extern "C" void kernel_launch(void* const* d_in, const int* in_sizes, int n_in,
                              void* d_out, int out_size, void* d_ws, size_t ws_size,
                              hipStream_t stream) {
    const float* x     = (const float*)d_in[0];
    const float* n1g   = (const float*)d_in[1];
    const float* n1b   = (const float*)d_in[2];
    const float* qkvw  = (const float*)d_in[3];
    const float* qkvb  = (const float*)d_in[4];
    const float* relb  = (const float*)d_in[5];
    const float* projw = (const float*)d_in[6];
    const float* projb = (const float*)d_in[7];
    const float* n2g   = (const float*)d_in[8];
    const float* n2b   = (const float*)d_in[9];
    const float* fc1w  = (const float*)d_in[10];
    const float* fc1b  = (const float*)d_in[11];
    const float* fc2w  = (const float*)d_in[12];
    const float* fc2b  = (const float*)d_in[13];
    float* out = (float*)d_out;

    const size_t NEL = (size_t)TOK * DIM;
    const size_t QKN = (size_t)NWIN * NHD * TPAD * 32;
    float* buf_x = (float*)d_ws;
    unsigned short* hbuf = (unsigned short*)(buf_x + NEL);  // LN1 out / attn out bf16
    unsigned short* lnb  = hbuf + NEL;                      // LN2 out bf16 (spatial order)
    unsigned short* bq   = lnb + NEL;        // [wh][352][32]
    unsigned short* bk   = bq + QKN;         // [wh][352][32]
    unsigned short* bv   = bk + QKN;         // [wh][32][352]  (V^T)
    unsigned short* wts  = bv + QKN;
    unsigned short* wq  = wts;                 // 2 x 27648
    unsigned short* wp  = wq + 2 * 27648;      // 2 x 9216
    unsigned short* w1  = wp + 2 * 9216;       // 2 x 36864
    unsigned short* w2  = w1 + 2 * 36864;      // 2 x 36864

    k_cvt<<<(2 * 27648 + 255) / 256, 256, 0, stream>>>(qkvw, wq, 2 * 27648);
    k_cvt<<<(2 * 9216  + 255) / 256, 256, 0, stream>>>(projw, wp, 2 * 9216);
    k_cvt<<<(2 * 36864 + 255) / 256, 256, 0, stream>>>(fc1w, w1, 2 * 36864);
    k_cvt<<<(2 * 36864 + 255) / 256, 256, 0, stream>>>(fc2w, w2, 2 * 36864);

    for (int L = 0; L < 2; ++L) {
        int shift = (L == 0) ? 0 : 3;
        const float* xin_l = (L == 0) ? x : buf_x;
        float* xmid = buf_x;
        float* xfin = (L == 0) ? buf_x : out;

        k_ln_part<<<TOK / 4, 256, 0, stream>>>(xin_l, n1g + L * 96, n1b + L * 96, hbuf, shift);
        k_qkv<<<TOK / 64, 256, 0, stream>>>(hbuf, wq + L * 27648, qkvb + L * 288, bq, bk, bv);
        k_attn<<<NWIN * NHD * 2, 256, 0, stream>>>(bq, bk, bv, relb + L * NBIAS * NHD, hbuf,
                                                   shift ? 1 : 0);
        k_proj<<<TOK / 64, 256, 0, stream>>>(hbuf, wp + L * 9216, projb + L * 96,
                                             xin_l, xmid, lnb,
                                             n2g + L * 96, n2b + L * 96, shift);
        k_mlp<<<TOK / 64, 256, 0, stream>>>(lnb, xmid, xfin,
                                            w1 + L * 36864, fc1b + L * 384,
                                            w2 + L * 36864, fc2b + L * 96);
    }
}

// Round 6
// 325.524 us; speedup vs baseline: 5.7232x; 1.3433x over previous
//
#include <hip/hip_runtime.h>
#include <math.h>

#define DIM 96
#define NHD 3
#define HD 32
#define NWT 343          // tokens per window
#define NWIN 128         // b * windows
#define TOK 43904        // total tokens = 2*28^3
#define NBIAS 2197       // (2*7-1)^3
#define SCALE 0.17677669529663687f
#define TPAD 352         // padded token count per window (22 tiles of 16)

typedef __attribute__((ext_vector_type(8))) short bf16x8;
typedef __attribute__((ext_vector_type(4))) float f32x4;

__device__ __forceinline__ float waveReduceSum(float v) {
    #pragma unroll
    for (int off = 32; off > 0; off >>= 1) v += __shfl_xor(v, off, 64);
    return v;
}

__device__ __forceinline__ unsigned short f2b(float f) {
    union { float f; unsigned int u; } x; x.f = f;
    unsigned int r = (x.u + 0x7fffu + ((x.u >> 16) & 1u)) >> 16;
    return (unsigned short)r;
}
__device__ __forceinline__ unsigned int pk2bf(float a, float b) {
    union { float f; unsigned int u; } x, y; x.f = a; y.f = b;
    return ((x.u + 0x8000u) >> 16) | ((y.u + 0x8000u) & 0xffff0000u);
}

// ---------------- K0: fp32 -> bf16 weight conversion ------------------------
__global__ void __launch_bounds__(256) k_cvt(const float* __restrict__ src,
                                             unsigned short* __restrict__ dst, int n) {
    int i = blockIdx.x * 256 + threadIdx.x;
    if (i < n) dst[i] = f2b(src[i]);
}

// ---------------- K1: LN1 + roll(-shift) + window partition -> bf16 ---------
__global__ void __launch_bounds__(256) k_ln_part(
        const float* __restrict__ x, const float* __restrict__ g,
        const float* __restrict__ bta, unsigned short* __restrict__ hw, int shift) {
    int wave = (blockIdx.x * blockDim.x + threadIdx.x) >> 6;
    int lane = threadIdx.x & 63;
    if (wave >= TOK) return;
    int bw = wave / NWT, n = wave % NWT;
    int b = bw >> 6, win = bw & 63;
    int wdi = win >> 4, whi = (win >> 2) & 3, wwi = win & 3;
    int d = n / 49, h = (n / 7) % 7, w = n % 7;
    int gd = wdi * 7 + d, gh = whi * 7 + h, gw = wwi * 7 + w;
    int sd = (gd + shift) % 28, sh = (gh + shift) % 28, sw = (gw + shift) % 28;
    const float* row = x + (((size_t)(b * 28 + sd) * 28 + sh) * 28 + sw) * DIM;
    float e0 = row[lane];
    float e1 = (lane < 32) ? row[64 + lane] : 0.0f;
    float s  = waveReduceSum(e0 + e1);
    float mu = s * (1.0f / 96.0f);
    float s2 = waveReduceSum(e0 * e0 + e1 * e1);
    float rstd = rsqrtf(s2 * (1.0f / 96.0f) - mu * mu + 1e-5f);
    unsigned short* dst = hw + (size_t)wave * DIM;
    dst[lane] = f2b((e0 - mu) * rstd * g[lane] + bta[lane]);
    if (lane < 32) dst[64 + lane] = f2b((e1 - mu) * rstd * g[64 + lane] + bta[64 + lane]);
}

// ---------------- K2: QKV MFMA GEMM -> bf16 q/k [wh][352][32], vT [wh][32][352]
__global__ void __launch_bounds__(256) k_qkv(
        const unsigned short* __restrict__ hw, const unsigned short* __restrict__ W,
        const float* __restrict__ bias, unsigned short* __restrict__ q,
        unsigned short* __restrict__ k, unsigned short* __restrict__ v) {
    int wid = threadIdx.x >> 6, lane = threadIdx.x & 63;
    int m0 = blockIdx.x * 64 + wid * 16;
    int lm = lane & 15, q4 = lane >> 4;
    f32x4 acc[18];
    #pragma unroll
    for (int c = 0; c < 18; ++c) acc[c] = (f32x4){0.f, 0.f, 0.f, 0.f};
    const unsigned short* arow = hw + (size_t)(m0 + lm) * 96;
    const unsigned short* brow = W + (size_t)lm * 96;
    #pragma unroll
    for (int ks = 0; ks < 3; ++ks) {
        bf16x8 a = *((const bf16x8*)(arow + ks * 32 + q4 * 8));
        const unsigned short* bp = brow + ks * 32 + q4 * 8;
        #pragma unroll
        for (int c = 0; c < 18; ++c) {
            bf16x8 b = *((const bf16x8*)(bp + c * 16 * 96));
            acc[c] = __builtin_amdgcn_mfma_f32_16x16x32_bf16(a, b, acc[c], 0, 0, 0);
        }
    }
    int bwr[4], nnr[4];
    #pragma unroll
    for (int r = 0; r < 4; ++r) {
        int tok = m0 + q4 * 4 + r;
        bwr[r] = tok / NWT; nnr[r] = tok % NWT;
    }
    #pragma unroll
    for (int c = 0; c < 18; ++c) {
        int n0 = c * 16;
        int which = n0 / 96;            // 0=q, 1=k, 2=v
        int col = (n0 % 96) + lm;       // 0..95
        int head = col >> 5, hd = col & 31;
        float bb = bias[n0 + lm];
        #pragma unroll
        for (int r = 0; r < 4; ++r) {
            int wh = bwr[r] * NHD + head;
            float val = acc[c][r] + bb;
            if (which == 0)
                q[(size_t)wh * (TPAD * 32) + nnr[r] * 32 + hd] = f2b(val * SCALE);
            else if (which == 1)
                k[(size_t)wh * (TPAD * 32) + nnr[r] * 32 + hd] = f2b(val);
            else
                v[(size_t)wh * (32 * TPAD) + hd * TPAD + nnr[r]] = f2b(val);
        }
    }
}

// ---------------- K3: MFMA flash attention ----------------------------------
__global__ void __launch_bounds__(256) k_attn(
        const unsigned short* __restrict__ q, const unsigned short* __restrict__ k,
        const unsigned short* __restrict__ vT, const float* __restrict__ rel,
        unsigned short* __restrict__ o, int shifted) {
    __shared__ float relh[NBIAS];
    __shared__ int   jinfo[NWT];
    __shared__ __align__(16) unsigned short vts[32 * 360];
    __shared__ __align__(16) unsigned short pbuf[4][16 * 40];
    __shared__ float dnm[4][16];
    int wh = blockIdx.x >> 1, half = blockIdx.x & 1;
    int bw = wh / NHD, head = wh % NHD;
    for (int i = threadIdx.x; i < NBIAS; i += 256) relh[i] = rel[i * NHD + head];
    const unsigned int* vsrc = (const unsigned int*)(vT + (size_t)wh * 32 * TPAD);
    unsigned int* vdst = (unsigned int*)vts;
    for (int i = threadIdx.x; i < 32 * 176; i += 256) {
        int row = i / 176, cc = i - row * 176;
        vdst[row * 180 + cc] = vsrc[i];
    }
    int win = bw & 63;
    int wdi = win >> 4, whi = (win >> 2) & 3, wwi = win & 3;
    for (int i = threadIdx.x; i < NWT; i += 256) {
        int d = i / 49, h = (i / 7) % 7, w = i % 7;
        int gd = wdi * 7 + d, gh = whi * 7 + h, gw = wwi * 7 + w;
        int rd = (gd < 21) ? 0 : ((gd < 25) ? 1 : 2);
        int rh = (gh < 21) ? 0 : ((gh < 25) ? 1 : 2);
        int rw = (gw < 21) ? 0 : ((gw < 25) ? 1 : 2);
        jinfo[i] = (d * 169 + h * 13 + w) | ((rd * 9 + rh * 3 + rw) << 16);
    }
    __syncthreads();
    int wid = threadIdx.x >> 6, lane = threadIdx.x & 63;
    int lm = lane & 15, q4 = lane >> 4;
    const unsigned short* qbase = q + (size_t)wh * TPAD * 32;
    const unsigned short* kbase = k + (size_t)wh * TPAD * 32;
    unsigned short* pb = pbuf[wid];
    for (int qtl = wid; qtl < 11; qtl += 4) {
        int qt = half * 11 + qtl;
        int qtok = qt * 16 + lm;
        bf16x8 qf = *((const bf16x8*)(qbase + qtok * 32 + q4 * 8));
        int jq = jinfo[min(qtok, NWT - 1)];
        int jqc = (jq & 0xffff) + 1098;
        int rq = jq >> 16;
        f32x4 acc0 = (f32x4){0.f, 0.f, 0.f, 0.f};
        f32x4 acc1 = (f32x4){0.f, 0.f, 0.f, 0.f};
        float denom = 0.f;
        for (int pr = 0; pr < 11; ++pr) {
            int kb0 = pr * 32;
            bf16x8 kf0 = *((const bf16x8*)(kbase + (kb0 + lm) * 32 + q4 * 8));
            bf16x8 kf1 = *((const bf16x8*)(kbase + (kb0 + 16 + lm) * 32 + q4 * 8));
            f32x4 z = (f32x4){0.f, 0.f, 0.f, 0.f};
            f32x4 s0 = __builtin_amdgcn_mfma_f32_16x16x32_bf16(kf0, qf, z, 0, 0, 0);
            f32x4 s1 = __builtin_amdgcn_mfma_f32_16x16x32_bf16(kf1, qf, z, 0, 0, 0);
            float p[8];
            #pragma unroll
            for (int t = 0; t < 2; ++t) {
                #pragma unroll
                for (int r = 0; r < 4; ++r) {
                    int key = kb0 + t * 16 + q4 * 4 + r;
                    int jk = jinfo[min(key, NWT - 1)];
                    float s = (t ? s1[r] : s0[r]) + relh[jqc - (jk & 0xffff)];
                    if (shifted && ((jk >> 16) != rq)) s -= 100.0f;
                    float pv = __expf(s);
                    pv = (key < NWT) ? pv : 0.0f;
                    p[t * 4 + r] = pv;
                    denom += pv;
                }
            }
            #pragma unroll
            for (int t = 0; t < 2; ++t) {
                *((unsigned int*)(pb + lm * 40 + t * 16 + q4 * 4)) =
                    pk2bf(p[t * 4 + 0], p[t * 4 + 1]);
                *((unsigned int*)(pb + lm * 40 + t * 16 + q4 * 4 + 2)) =
                    pk2bf(p[t * 4 + 2], p[t * 4 + 3]);
            }
            bf16x8 pf = *((const bf16x8*)(pb + lm * 40 + q4 * 8));
            bf16x8 v0 = *((const bf16x8*)(vts + lm * 360 + kb0 + q4 * 8));
            bf16x8 v1 = *((const bf16x8*)(vts + (16 + lm) * 360 + kb0 + q4 * 8));
            acc0 = __builtin_amdgcn_mfma_f32_16x16x32_bf16(pf, v0, acc0, 0, 0, 0);
            acc1 = __builtin_amdgcn_mfma_f32_16x16x32_bf16(pf, v1, acc1, 0, 0, 0);
        }
        denom += __shfl_xor(denom, 16, 64);
        denom += __shfl_xor(denom, 32, 64);
        if (lane < 16) dnm[wid][lm] = denom;
        #pragma unroll
        for (int r = 0; r < 4; ++r) {
            int qrow = qt * 16 + q4 * 4 + r;
            if (qrow < NWT) {
                float inv = 1.0f / dnm[wid][q4 * 4 + r];
                unsigned short* op = o + (size_t)(bw * NWT + qrow) * DIM + head * HD;
                op[lm]      = f2b(acc0[r] * inv);
                op[16 + lm] = f2b(acc1[r] * inv);
            }
        }
    }
}

// ---------------- K4: proj MFMA + reverse/roll + residual + LN2 -> bf16 -----
__global__ void __launch_bounds__(256) k_proj(
        const unsigned short* __restrict__ ao, const unsigned short* __restrict__ W,
        const float* __restrict__ bias, const float* __restrict__ xin,
        float* __restrict__ xout, unsigned short* __restrict__ lnb,
        const float* __restrict__ g2, const float* __restrict__ b2, int shift) {
    int wid = threadIdx.x >> 6, lane = threadIdx.x & 63;
    int m0 = blockIdx.x * 64 + wid * 16;
    int lm = lane & 15, q4 = lane >> 4;
    f32x4 acc[6];
    #pragma unroll
    for (int c = 0; c < 6; ++c) acc[c] = (f32x4){0.f, 0.f, 0.f, 0.f};
    const unsigned short* arow = ao + (size_t)(m0 + lm) * 96;
    const unsigned short* brow = W + (size_t)lm * 96;
    #pragma unroll
    for (int ks = 0; ks < 3; ++ks) {
        bf16x8 a = *((const bf16x8*)(arow + ks * 32 + q4 * 8));
        const unsigned short* bp = brow + ks * 32 + q4 * 8;
        #pragma unroll
        for (int c = 0; c < 6; ++c) {
            bf16x8 b = *((const bf16x8*)(bp + c * 16 * 96));
            acc[c] = __builtin_amdgcn_mfma_f32_16x16x32_bf16(a, b, acc[c], 0, 0, 0);
        }
    }
    size_t rowoff[4];
    #pragma unroll
    for (int r = 0; r < 4; ++r) {
        int wtok = m0 + q4 * 4 + r;
        int bw = wtok / NWT, n = wtok % NWT;
        int b = bw >> 6, win = bw & 63;
        int wdi = win >> 4, whi = (win >> 2) & 3, wwi = win & 3;
        int d = n / 49, h = (n / 7) % 7, w = n % 7;
        int sd = (wdi * 7 + d + shift) % 28;
        int sh = (whi * 7 + h + shift) % 28;
        int sw = (wwi * 7 + w + shift) % 28;
        rowoff[r] = (((size_t)(b * 28 + sd) * 28 + sh) * 28 + sw) * 96;
    }
    float val[6][4];
    float g2v[6], b2v[6];
    #pragma unroll
    for (int c = 0; c < 6; ++c) {
        int n = c * 16 + lm;
        float bb = bias[n];
        g2v[c] = g2[n]; b2v[c] = b2[n];
        #pragma unroll
        for (int r = 0; r < 4; ++r) {
            size_t off = rowoff[r] + n;
            float y = xin[off] + acc[c][r] + bb;
            val[c][r] = y;
            xout[off] = y;
        }
    }
    #pragma unroll
    for (int r = 0; r < 4; ++r) {
        float s = 0.f, s2 = 0.f;
        #pragma unroll
        for (int c = 0; c < 6; ++c) { s += val[c][r]; s2 += val[c][r] * val[c][r]; }
        #pragma unroll
        for (int off = 8; off > 0; off >>= 1) {
            s  += __shfl_xor(s,  off, 64);
            s2 += __shfl_xor(s2, off, 64);
        }
        float mu = s * (1.0f / 96.0f);
        float rstd = rsqrtf(s2 * (1.0f / 96.0f) - mu * mu + 1e-5f);
        #pragma unroll
        for (int c = 0; c < 6; ++c) {
            lnb[rowoff[r] + c * 16 + lm] =
                f2b((val[c][r] - mu) * rstd * g2v[c] + b2v[c]);
        }
    }
}

// ---------------- K5: MLP MFMA, chunked LDS-staged fc1->fc2 fusion ----------
// per chunk of 64 hidden cols: stage w1 rows + w2 k-window in LDS (shared by
// 4 waves), fc1 MFMA -> GELU -> tiny per-wave hid tile -> fc2 partial MFMA.
__global__ void __launch_bounds__(256) k_mlp(
        const unsigned short* __restrict__ lnb, const float* __restrict__ xmid,
        float* __restrict__ xout,
        const unsigned short* __restrict__ w1, const float* __restrict__ bb1,
        const unsigned short* __restrict__ w2, const float* __restrict__ bb2) {
    __shared__ __align__(16) unsigned short w1s[64][104];   // 13312 B, stride 52 dw -> 2-way
    __shared__ __align__(16) unsigned short w2s[96][76];    // 14592 B, stride 38 dw -> 1-way
    __shared__ __align__(16) unsigned short hid[4][16][76]; //  9728 B per-wave tiles
    int wid = threadIdx.x >> 6, lane = threadIdx.x & 63;
    int lm = lane & 15, q4 = lane >> 4;
    int m0w = blockIdx.x * 64 + wid * 16;
    // fc1 A-frags (token rows) held in registers for all chunks
    bf16x8 a1[3];
    const unsigned short* arow = lnb + (size_t)(m0w + lm) * 96;
    #pragma unroll
    for (int ks = 0; ks < 3; ++ks)
        a1[ks] = *((const bf16x8*)(arow + ks * 32 + q4 * 8));
    f32x4 acc2[6];
    #pragma unroll
    for (int c = 0; c < 6; ++c) acc2[c] = (f32x4){0.f, 0.f, 0.f, 0.f};
    unsigned short* hw_ = &hid[wid][0][0];
    for (int ch = 0; ch < 6; ++ch) {
        __syncthreads();
        // stage w1 chunk rows [ch*64, ch*64+64) x 96 -- source fully contiguous
        const uint4* src1 = (const uint4*)(w1 + ch * 64 * 96);
        #pragma unroll
        for (int t = 0; t < 3; ++t) {
            int s = threadIdx.x + t * 256;     // 0..767
            int row = s / 12, seg = s % 12;
            *((uint4*)&w1s[row][seg * 8]) = src1[s];
        }
        // stage w2 k-window [0..96) x [ch*64, ch*64+64)
        #pragma unroll
        for (int t = 0; t < 3; ++t) {
            int s = threadIdx.x + t * 256;
            int row = s >> 3, seg = s & 7;
            *((uint4*)&w2s[row][seg * 8]) =
                *((const uint4*)(w2 + row * 384 + ch * 64 + seg * 8));
        }
        __syncthreads();
        // fc1 for this 64-col chunk
        f32x4 acc1[4];
        #pragma unroll
        for (int t = 0; t < 4; ++t) acc1[t] = (f32x4){0.f, 0.f, 0.f, 0.f};
        #pragma unroll
        for (int ks = 0; ks < 3; ++ks) {
            #pragma unroll
            for (int t = 0; t < 4; ++t) {
                bf16x8 b = *((const bf16x8*)&w1s[t * 16 + lm][ks * 32 + q4 * 8]);
                acc1[t] = __builtin_amdgcn_mfma_f32_16x16x32_bf16(a1[ks], b, acc1[t], 0, 0, 0);
            }
        }
        // GELU -> per-wave hid tile (row=token-in-16, col=k-in-chunk)
        #pragma unroll
        for (int t = 0; t < 4; ++t) {
            float bb = bb1[ch * 64 + t * 16 + lm];
            #pragma unroll
            for (int r = 0; r < 4; ++r) {
                float v2 = acc1[t][r] + bb;
                float ge = 0.5f * v2 * (1.0f + erff(v2 * 0.70710678118654752f));
                hw_[(q4 * 4 + r) * 76 + t * 16 + lm] = f2b(ge);
            }
        }
        // fc2 partial over this 64-wide k-window (same-wave LDS, lgkmcnt only)
        #pragma unroll
        for (int ks2 = 0; ks2 < 2; ++ks2) {
            bf16x8 a = *((const bf16x8*)(hw_ + lm * 76 + ks2 * 32 + q4 * 8));
            #pragma unroll
            for (int c = 0; c < 6; ++c) {
                bf16x8 b = *((const bf16x8*)&w2s[c * 16 + lm][ks2 * 32 + q4 * 8]);
                acc2[c] = __builtin_amdgcn_mfma_f32_16x16x32_bf16(a, b, acc2[c], 0, 0, 0);
            }
        }
    }
    #pragma unroll
    for (int c = 0; c < 6; ++c) {
        int n = c * 16 + lm;
        float bb = bb2[n];
        #pragma unroll
        for (int r = 0; r < 4; ++r) {
            size_t off = (size_t)(m0w + q4 * 4 + r) * 96 + n;
            xout[off] = xmid[off] + acc2[c][r] + bb;
        }
    }
}

extern "C" void kernel_launch(void* const* d_in, const int* in_sizes, int n_in,
                              void* d_out, int out_size, void* d_ws, size_t ws_size,
                              hipStream_t stream) {
    const float* x     = (const float*)d_in[0];
    const float* n1g   = (const float*)d_in[1];
    const float* n1b   = (const float*)d_in[2];
    const float* qkvw  = (const float*)d_in[3];
    const float* qkvb  = (const float*)d_in[4];
    const float* relb  = (const float*)d_in[5];
    const float* projw = (const float*)d_in[6];
    const float* projb = (const float*)d_in[7];
    const float* n2g   = (const float*)d_in[8];
    const float* n2b   = (const float*)d_in[9];
    const float* fc1w  = (const float*)d_in[10];
    const float* fc1b  = (const float*)d_in[11];
    const float* fc2w  = (const float*)d_in[12];
    const float* fc2b  = (const float*)d_in[13];
    float* out = (float*)d_out;

    const size_t NEL = (size_t)TOK * DIM;
    const size_t QKN = (size_t)NWIN * NHD * TPAD * 32;
    float* buf_x = (float*)d_ws;
    unsigned short* hbuf = (unsigned short*)(buf_x + NEL);  // LN1 out / attn out bf16
    unsigned short* lnb  = hbuf + NEL;                      // LN2 out bf16 (spatial order)
    unsigned short* bq   = lnb + NEL;        // [wh][352][32]
    unsigned short* bk   = bq + QKN;         // [wh][352][32]
    unsigned short* bv   = bk + QKN;         // [wh][32][352]  (V^T)
    unsigned short* wts  = bv + QKN;
    unsigned short* wq  = wts;                 // 2 x 27648
    unsigned short* wp  = wq + 2 * 27648;      // 2 x 9216
    unsigned short* w1  = wp + 2 * 9216;       // 2 x 36864
    unsigned short* w2  = w1 + 2 * 36864;      // 2 x 36864

    k_cvt<<<(2 * 27648 + 255) / 256, 256, 0, stream>>>(qkvw, wq, 2 * 27648);
    k_cvt<<<(2 * 9216  + 255) / 256, 256, 0, stream>>>(projw, wp, 2 * 9216);
    k_cvt<<<(2 * 36864 + 255) / 256, 256, 0, stream>>>(fc1w, w1, 2 * 36864);
    k_cvt<<<(2 * 36864 + 255) / 256, 256, 0, stream>>>(fc2w, w2, 2 * 36864);

    for (int L = 0; L < 2; ++L) {
        int shift = (L == 0) ? 0 : 3;
        const float* xin_l = (L == 0) ? x : buf_x;
        float* xmid = buf_x;
        float* xfin = (L == 0) ? buf_x : out;

        k_ln_part<<<TOK / 4, 256, 0, stream>>>(xin_l, n1g + L * 96, n1b + L * 96, hbuf, shift);
        k_qkv<<<TOK / 64, 256, 0, stream>>>(hbuf, wq + L * 27648, qkvb + L * 288, bq, bk, bv);
        k_attn<<<NWIN * NHD * 2, 256, 0, stream>>>(bq, bk, bv, relb + L * NBIAS * NHD, hbuf,
                                                   shift ? 1 : 0);
        k_proj<<<TOK / 64, 256, 0, stream>>>(hbuf, wp + L * 9216, projb + L * 96,
                                             xin_l, buf_x, lnb,
                                             n2g + L * 96, n2b + L * 96, shift);
        k_mlp<<<TOK / 64, 256, 0, stream>>>(lnb, buf_x, xfin,
                                            w1 + L * 36864, fc1b + L * 384,
                                            w2 + L * 36864, fc2b + L * 96);
    }
}

// Round 7
// 295.484 us; speedup vs baseline: 6.3050x; 1.1017x over previous
//
#include <hip/hip_runtime.h>
#include <math.h>

#define DIM 96
#define NHD 3
#define HD 32
#define NWT 343          // tokens per window
#define NWIN 128         // b * windows
#define TOK 43904        // total tokens = 2*28^3
#define NBIAS 2197       // (2*7-1)^3
#define SCALE 0.17677669529663687f
#define TPAD 352         // padded token count per window (22 tiles of 16)

typedef __attribute__((ext_vector_type(8))) short bf16x8;
typedef __attribute__((ext_vector_type(4))) float f32x4;

__device__ __forceinline__ unsigned short f2b(float f) {
    union { float f; unsigned int u; } x; x.f = f;
    unsigned int r = (x.u + 0x7fffu + ((x.u >> 16) & 1u)) >> 16;
    return (unsigned short)r;
}
__device__ __forceinline__ unsigned int pk2bf(float a, float b) {
    union { float f; unsigned int u; } x, y; x.f = a; y.f = b;
    return ((x.u + 0x8000u) >> 16) | ((y.u + 0x8000u) & 0xffff0000u);
}

// ---------------- K0: fp32 -> bf16 weight conversion ------------------------
__global__ void __launch_bounds__(256) k_cvt(const float* __restrict__ src,
                                             unsigned short* __restrict__ dst, int n) {
    int i = blockIdx.x * 256 + threadIdx.x;
    if (i < n) dst[i] = f2b(src[i]);
}

// ---------------- K2: fused LN1 + roll + partition + QKV MFMA ---------------
// block = 64 tokens (4 waves); LN1 computed in-register (proj-style 16-lane
// shuffle reduce), bf16 rows -> LDS, W staged in 3 LDS chunks shared by waves.
__global__ void __launch_bounds__(256) k_qkv(
        const float* __restrict__ x, const float* __restrict__ g1,
        const float* __restrict__ b1, const unsigned short* __restrict__ W,
        const float* __restrict__ bias, unsigned short* __restrict__ q,
        unsigned short* __restrict__ k, unsigned short* __restrict__ v, int shift) {
    __shared__ __align__(16) unsigned short lns[64][104];   // 13312 B
    __shared__ __align__(16) unsigned short wbuf[96][104];  // 19968 B
    int wid = threadIdx.x >> 6, lane = threadIdx.x & 63;
    int lm = lane & 15, q4 = lane >> 4;
    int m0 = blockIdx.x * 64 + wid * 16;
    int bwr[4], nnr[4];
    size_t rowoff[4];
    #pragma unroll
    for (int r = 0; r < 4; ++r) {
        int wtok = m0 + q4 * 4 + r;
        int bw = wtok / NWT, n = wtok % NWT;
        bwr[r] = bw; nnr[r] = n;
        int b = bw >> 6, win = bw & 63;
        int wdi = win >> 4, whi = (win >> 2) & 3, wwi = win & 3;
        int d = n / 49, h = (n / 7) % 7, w = n % 7;
        int sd = (wdi * 7 + d + shift) % 28;
        int sh = (whi * 7 + h + shift) % 28;
        int sw = (wwi * 7 + w + shift) % 28;
        rowoff[r] = (((size_t)(b * 28 + sd) * 28 + sh) * 28 + sw) * 96;
    }
    // LN1: cols c*16+lm held across 16 lm lanes, reduce via shfl_xor 8/4/2/1
    float val[6][4], g1v[6], b1v[6];
    #pragma unroll
    for (int c = 0; c < 6; ++c) {
        int ncol = c * 16 + lm;
        g1v[c] = g1[ncol]; b1v[c] = b1[ncol];
        #pragma unroll
        for (int r = 0; r < 4; ++r) val[c][r] = x[rowoff[r] + ncol];
    }
    #pragma unroll
    for (int r = 0; r < 4; ++r) {
        float s = 0.f, s2 = 0.f;
        #pragma unroll
        for (int c = 0; c < 6; ++c) { s += val[c][r]; s2 += val[c][r] * val[c][r]; }
        #pragma unroll
        for (int off = 8; off > 0; off >>= 1) {
            s  += __shfl_xor(s,  off, 64);
            s2 += __shfl_xor(s2, off, 64);
        }
        float mu = s * (1.0f / 96.0f);
        float rstd = rsqrtf(s2 * (1.0f / 96.0f) - mu * mu + 1e-5f);
        int row = wid * 16 + q4 * 4 + r;
        #pragma unroll
        for (int c = 0; c < 6; ++c)
            lns[row][c * 16 + lm] = f2b((val[c][r] - mu) * rstd * g1v[c] + b1v[c]);
    }
    __syncthreads();
    bf16x8 a1[3];
    #pragma unroll
    for (int ks = 0; ks < 3; ++ks)
        a1[ks] = *((const bf16x8*)&lns[wid * 16 + lm][ks * 32 + q4 * 8]);
    for (int ch = 0; ch < 3; ++ch) {
        __syncthreads();
        const uint4* src = (const uint4*)(W + ch * 96 * 96);
        for (int s = threadIdx.x; s < 1152; s += 256) {
            int row = s / 12, seg = s % 12;
            *((uint4*)&wbuf[row][seg * 8]) = src[s];
        }
        __syncthreads();
        f32x4 acc[6];
        #pragma unroll
        for (int c = 0; c < 6; ++c) acc[c] = (f32x4){0.f, 0.f, 0.f, 0.f};
        #pragma unroll
        for (int ks = 0; ks < 3; ++ks) {
            #pragma unroll
            for (int c = 0; c < 6; ++c) {
                bf16x8 b = *((const bf16x8*)&wbuf[c * 16 + lm][ks * 32 + q4 * 8]);
                acc[c] = __builtin_amdgcn_mfma_f32_16x16x32_bf16(a1[ks], b, acc[c], 0, 0, 0);
            }
        }
        #pragma unroll
        for (int c = 0; c < 6; ++c) {
            int col = c * 16 + lm;          // 0..95 within the qkv third
            int head = col >> 5, hd = col & 31;
            float bb = bias[ch * 96 + col];
            #pragma unroll
            for (int r = 0; r < 4; ++r) {
                int wh = bwr[r] * NHD + head;
                float vv = acc[c][r] + bb;
                if (ch == 0)
                    q[(size_t)wh * (TPAD * 32) + nnr[r] * 32 + hd] = f2b(vv * SCALE);
                else if (ch == 1)
                    k[(size_t)wh * (TPAD * 32) + nnr[r] * 32 + hd] = f2b(vv);
                else
                    v[(size_t)wh * (32 * TPAD) + hd * TPAD + nnr[r]] = f2b(vv);
            }
        }
    }
}

// ---------------- K3: MFMA flash attention ----------------------------------
__global__ void __launch_bounds__(256) k_attn(
        const unsigned short* __restrict__ q, const unsigned short* __restrict__ k,
        const unsigned short* __restrict__ vT, const float* __restrict__ rel,
        unsigned short* __restrict__ o, int shifted) {
    __shared__ float relh[NBIAS];
    __shared__ int   jinfo[NWT];
    __shared__ __align__(16) unsigned short vts[32 * 360];
    __shared__ __align__(16) unsigned short pbuf[4][16 * 40];
    __shared__ float dnm[4][16];
    int wh = blockIdx.x >> 1, half = blockIdx.x & 1;
    int bw = wh / NHD, head = wh % NHD;
    for (int i = threadIdx.x; i < NBIAS; i += 256) relh[i] = rel[i * NHD + head];
    const unsigned int* vsrc = (const unsigned int*)(vT + (size_t)wh * 32 * TPAD);
    unsigned int* vdst = (unsigned int*)vts;
    for (int i = threadIdx.x; i < 32 * 176; i += 256) {
        int row = i / 176, cc = i - row * 176;
        vdst[row * 180 + cc] = vsrc[i];
    }
    int win = bw & 63;
    int wdi = win >> 4, whi = (win >> 2) & 3, wwi = win & 3;
    for (int i = threadIdx.x; i < NWT; i += 256) {
        int d = i / 49, h = (i / 7) % 7, w = i % 7;
        int gd = wdi * 7 + d, gh = whi * 7 + h, gw = wwi * 7 + w;
        int rd = (gd < 21) ? 0 : ((gd < 25) ? 1 : 2);
        int rh = (gh < 21) ? 0 : ((gh < 25) ? 1 : 2);
        int rw = (gw < 21) ? 0 : ((gw < 25) ? 1 : 2);
        jinfo[i] = (d * 169 + h * 13 + w) | ((rd * 9 + rh * 3 + rw) << 16);
    }
    __syncthreads();
    int wid = threadIdx.x >> 6, lane = threadIdx.x & 63;
    int lm = lane & 15, q4 = lane >> 4;
    const unsigned short* qbase = q + (size_t)wh * TPAD * 32;
    const unsigned short* kbase = k + (size_t)wh * TPAD * 32;
    unsigned short* pb = pbuf[wid];
    for (int qtl = wid; qtl < 11; qtl += 4) {
        int qt = half * 11 + qtl;
        int qtok = qt * 16 + lm;
        bf16x8 qf = *((const bf16x8*)(qbase + qtok * 32 + q4 * 8));
        int jq = jinfo[min(qtok, NWT - 1)];
        int jqc = (jq & 0xffff) + 1098;
        int rq = jq >> 16;
        f32x4 acc0 = (f32x4){0.f, 0.f, 0.f, 0.f};
        f32x4 acc1 = (f32x4){0.f, 0.f, 0.f, 0.f};
        float denom = 0.f;
        for (int pr = 0; pr < 11; ++pr) {
            int kb0 = pr * 32;
            bf16x8 kf0 = *((const bf16x8*)(kbase + (kb0 + lm) * 32 + q4 * 8));
            bf16x8 kf1 = *((const bf16x8*)(kbase + (kb0 + 16 + lm) * 32 + q4 * 8));
            f32x4 z = (f32x4){0.f, 0.f, 0.f, 0.f};
            f32x4 s0 = __builtin_amdgcn_mfma_f32_16x16x32_bf16(kf0, qf, z, 0, 0, 0);
            f32x4 s1 = __builtin_amdgcn_mfma_f32_16x16x32_bf16(kf1, qf, z, 0, 0, 0);
            float p[8];
            #pragma unroll
            for (int t = 0; t < 2; ++t) {
                #pragma unroll
                for (int r = 0; r < 4; ++r) {
                    int key = kb0 + t * 16 + q4 * 4 + r;
                    int jk = jinfo[min(key, NWT - 1)];
                    float s = (t ? s1[r] : s0[r]) + relh[jqc - (jk & 0xffff)];
                    if (shifted && ((jk >> 16) != rq)) s -= 100.0f;
                    float pv = __expf(s);
                    pv = (key < NWT) ? pv : 0.0f;
                    p[t * 4 + r] = pv;
                    denom += pv;
                }
            }
            #pragma unroll
            for (int t = 0; t < 2; ++t) {
                *((unsigned int*)(pb + lm * 40 + t * 16 + q4 * 4)) =
                    pk2bf(p[t * 4 + 0], p[t * 4 + 1]);
                *((unsigned int*)(pb + lm * 40 + t * 16 + q4 * 4 + 2)) =
                    pk2bf(p[t * 4 + 2], p[t * 4 + 3]);
            }
            bf16x8 pf = *((const bf16x8*)(pb + lm * 40 + q4 * 8));
            bf16x8 v0 = *((const bf16x8*)(vts + lm * 360 + kb0 + q4 * 8));
            bf16x8 v1 = *((const bf16x8*)(vts + (16 + lm) * 360 + kb0 + q4 * 8));
            acc0 = __builtin_amdgcn_mfma_f32_16x16x32_bf16(pf, v0, acc0, 0, 0, 0);
            acc1 = __builtin_amdgcn_mfma_f32_16x16x32_bf16(pf, v1, acc1, 0, 0, 0);
        }
        denom += __shfl_xor(denom, 16, 64);
        denom += __shfl_xor(denom, 32, 64);
        if (lane < 16) dnm[wid][lm] = denom;
        #pragma unroll
        for (int r = 0; r < 4; ++r) {
            int qrow = qt * 16 + q4 * 4 + r;
            if (qrow < NWT) {
                float inv = 1.0f / dnm[wid][q4 * 4 + r];
                unsigned short* op = o + (size_t)(bw * NWT + qrow) * DIM + head * HD;
                op[lm]      = f2b(acc0[r] * inv);
                op[16 + lm] = f2b(acc1[r] * inv);
            }
        }
    }
}

// ---------------- K4: proj MFMA (W in LDS) + reverse/roll + residual + LN2 --
__global__ void __launch_bounds__(256) k_proj(
        const unsigned short* __restrict__ ao, const unsigned short* __restrict__ W,
        const float* __restrict__ bias, const float* __restrict__ xin,
        float* __restrict__ xout, unsigned short* __restrict__ lnb,
        const float* __restrict__ g2, const float* __restrict__ b2, int shift) {
    __shared__ __align__(16) unsigned short wbuf[96][104];  // 19968 B
    for (int s = threadIdx.x; s < 1152; s += 256) {
        int row = s / 12, seg = s % 12;
        *((uint4*)&wbuf[row][seg * 8]) = ((const uint4*)W)[s];
    }
    int wid = threadIdx.x >> 6, lane = threadIdx.x & 63;
    int m0 = blockIdx.x * 64 + wid * 16;
    int lm = lane & 15, q4 = lane >> 4;
    const unsigned short* arow = ao + (size_t)(m0 + lm) * 96;
    bf16x8 a1[3];
    #pragma unroll
    for (int ks = 0; ks < 3; ++ks)
        a1[ks] = *((const bf16x8*)(arow + ks * 32 + q4 * 8));
    __syncthreads();
    f32x4 acc[6];
    #pragma unroll
    for (int c = 0; c < 6; ++c) acc[c] = (f32x4){0.f, 0.f, 0.f, 0.f};
    #pragma unroll
    for (int ks = 0; ks < 3; ++ks) {
        #pragma unroll
        for (int c = 0; c < 6; ++c) {
            bf16x8 b = *((const bf16x8*)&wbuf[c * 16 + lm][ks * 32 + q4 * 8]);
            acc[c] = __builtin_amdgcn_mfma_f32_16x16x32_bf16(a1[ks], b, acc[c], 0, 0, 0);
        }
    }
    size_t rowoff[4];
    #pragma unroll
    for (int r = 0; r < 4; ++r) {
        int wtok = m0 + q4 * 4 + r;
        int bw = wtok / NWT, n = wtok % NWT;
        int b = bw >> 6, win = bw & 63;
        int wdi = win >> 4, whi = (win >> 2) & 3, wwi = win & 3;
        int d = n / 49, h = (n / 7) % 7, w = n % 7;
        int sd = (wdi * 7 + d + shift) % 28;
        int sh = (whi * 7 + h + shift) % 28;
        int sw = (wwi * 7 + w + shift) % 28;
        rowoff[r] = (((size_t)(b * 28 + sd) * 28 + sh) * 28 + sw) * 96;
    }
    float val[6][4];
    float g2v[6], b2v[6];
    #pragma unroll
    for (int c = 0; c < 6; ++c) {
        int n = c * 16 + lm;
        float bb = bias[n];
        g2v[c] = g2[n]; b2v[c] = b2[n];
        #pragma unroll
        for (int r = 0; r < 4; ++r) {
            size_t off = rowoff[r] + n;
            float y = xin[off] + acc[c][r] + bb;
            val[c][r] = y;
            xout[off] = y;
        }
    }
    #pragma unroll
    for (int r = 0; r < 4; ++r) {
        float s = 0.f, s2 = 0.f;
        #pragma unroll
        for (int c = 0; c < 6; ++c) { s += val[c][r]; s2 += val[c][r] * val[c][r]; }
        #pragma unroll
        for (int off = 8; off > 0; off >>= 1) {
            s  += __shfl_xor(s,  off, 64);
            s2 += __shfl_xor(s2, off, 64);
        }
        float mu = s * (1.0f / 96.0f);
        float rstd = rsqrtf(s2 * (1.0f / 96.0f) - mu * mu + 1e-5f);
        #pragma unroll
        for (int c = 0; c < 6; ++c) {
            lnb[rowoff[r] + c * 16 + lm] =
                f2b((val[c][r] - mu) * rstd * g2v[c] + b2v[c]);
        }
    }
}

// ---------------- K5: MLP MFMA, chunked LDS-staged fc1->fc2 fusion ----------
__global__ void __launch_bounds__(256) k_mlp(
        const unsigned short* __restrict__ lnb, const float* __restrict__ xmid,
        float* __restrict__ xout,
        const unsigned short* __restrict__ w1, const float* __restrict__ bb1,
        const unsigned short* __restrict__ w2, const float* __restrict__ bb2) {
    __shared__ __align__(16) unsigned short w1s[64][104];   // 13312 B
    __shared__ __align__(16) unsigned short w2s[96][76];    // 14592 B
    __shared__ __align__(16) unsigned short hid[4][16][76]; //  9728 B per-wave tiles
    int wid = threadIdx.x >> 6, lane = threadIdx.x & 63;
    int lm = lane & 15, q4 = lane >> 4;
    int m0w = blockIdx.x * 64 + wid * 16;
    bf16x8 a1[3];
    const unsigned short* arow = lnb + (size_t)(m0w + lm) * 96;
    #pragma unroll
    for (int ks = 0; ks < 3; ++ks)
        a1[ks] = *((const bf16x8*)(arow + ks * 32 + q4 * 8));
    f32x4 acc2[6];
    #pragma unroll
    for (int c = 0; c < 6; ++c) acc2[c] = (f32x4){0.f, 0.f, 0.f, 0.f};
    unsigned short* hw_ = &hid[wid][0][0];
    for (int ch = 0; ch < 6; ++ch) {
        __syncthreads();
        const uint4* src1 = (const uint4*)(w1 + ch * 64 * 96);
        #pragma unroll
        for (int t = 0; t < 3; ++t) {
            int s = threadIdx.x + t * 256;
            int row = s / 12, seg = s % 12;
            *((uint4*)&w1s[row][seg * 8]) = src1[s];
        }
        #pragma unroll
        for (int t = 0; t < 3; ++t) {
            int s = threadIdx.x + t * 256;
            int row = s >> 3, seg = s & 7;
            *((uint4*)&w2s[row][seg * 8]) =
                *((const uint4*)(w2 + row * 384 + ch * 64 + seg * 8));
        }
        __syncthreads();
        f32x4 acc1[4];
        #pragma unroll
        for (int t = 0; t < 4; ++t) acc1[t] = (f32x4){0.f, 0.f, 0.f, 0.f};
        #pragma unroll
        for (int ks = 0; ks < 3; ++ks) {
            #pragma unroll
            for (int t = 0; t < 4; ++t) {
                bf16x8 b = *((const bf16x8*)&w1s[t * 16 + lm][ks * 32 + q4 * 8]);
                acc1[t] = __builtin_amdgcn_mfma_f32_16x16x32_bf16(a1[ks], b, acc1[t], 0, 0, 0);
            }
        }
        #pragma unroll
        for (int t = 0; t < 4; ++t) {
            float bb = bb1[ch * 64 + t * 16 + lm];
            #pragma unroll
            for (int r = 0; r < 4; ++r) {
                float v2 = acc1[t][r] + bb;
                float ge = 0.5f * v2 * (1.0f + erff(v2 * 0.70710678118654752f));
                hw_[(q4 * 4 + r) * 76 + t * 16 + lm] = f2b(ge);
            }
        }
        #pragma unroll
        for (int ks2 = 0; ks2 < 2; ++ks2) {
            bf16x8 a = *((const bf16x8*)(hw_ + lm * 76 + ks2 * 32 + q4 * 8));
            #pragma unroll
            for (int c = 0; c < 6; ++c) {
                bf16x8 b = *((const bf16x8*)&w2s[c * 16 + lm][ks2 * 32 + q4 * 8]);
                acc2[c] = __builtin_amdgcn_mfma_f32_16x16x32_bf16(a, b, acc2[c], 0, 0, 0);
            }
        }
    }
    #pragma unroll
    for (int c = 0; c < 6; ++c) {
        int n = c * 16 + lm;
        float bb = bb2[n];
        #pragma unroll
        for (int r = 0; r < 4; ++r) {
            size_t off = (size_t)(m0w + q4 * 4 + r) * 96 + n;
            xout[off] = xmid[off] + acc2[c][r] + bb;
        }
    }
}

extern "C" void kernel_launch(void* const* d_in, const int* in_sizes, int n_in,
                              void* d_out, int out_size, void* d_ws, size_t ws_size,
                              hipStream_t stream) {
    const float* x     = (const float*)d_in[0];
    const float* n1g   = (const float*)d_in[1];
    const float* n1b   = (const float*)d_in[2];
    const float* qkvw  = (const float*)d_in[3];
    const float* qkvb  = (const float*)d_in[4];
    const float* relb  = (const float*)d_in[5];
    const float* projw = (const float*)d_in[6];
    const float* projb = (const float*)d_in[7];
    const float* n2g   = (const float*)d_in[8];
    const float* n2b   = (const float*)d_in[9];
    const float* fc1w  = (const float*)d_in[10];
    const float* fc1b  = (const float*)d_in[11];
    const float* fc2w  = (const float*)d_in[12];
    const float* fc2b  = (const float*)d_in[13];
    float* out = (float*)d_out;

    const size_t NEL = (size_t)TOK * DIM;
    const size_t QKN = (size_t)NWIN * NHD * TPAD * 32;
    float* buf_x = (float*)d_ws;
    unsigned short* hbuf = (unsigned short*)(buf_x + NEL);  // attn out bf16 [tok][96]
    unsigned short* lnb  = hbuf + NEL;                      // LN2 out bf16 (spatial order)
    unsigned short* bq   = lnb + NEL;        // [wh][352][32]
    unsigned short* bk   = bq + QKN;         // [wh][352][32]
    unsigned short* bv   = bk + QKN;         // [wh][32][352]  (V^T)
    unsigned short* wts  = bv + QKN;
    unsigned short* wq  = wts;                 // 2 x 27648
    unsigned short* wp  = wq + 2 * 27648;      // 2 x 9216
    unsigned short* w1  = wp + 2 * 9216;       // 2 x 36864
    unsigned short* w2  = w1 + 2 * 36864;      // 2 x 36864

    k_cvt<<<(2 * 27648 + 255) / 256, 256, 0, stream>>>(qkvw, wq, 2 * 27648);
    k_cvt<<<(2 * 9216  + 255) / 256, 256, 0, stream>>>(projw, wp, 2 * 9216);
    k_cvt<<<(2 * 36864 + 255) / 256, 256, 0, stream>>>(fc1w, w1, 2 * 36864);
    k_cvt<<<(2 * 36864 + 255) / 256, 256, 0, stream>>>(fc2w, w2, 2 * 36864);

    for (int L = 0; L < 2; ++L) {
        int shift = (L == 0) ? 0 : 3;
        const float* xin_l = (L == 0) ? x : buf_x;
        float* xfin = (L == 0) ? buf_x : out;

        k_qkv<<<TOK / 64, 256, 0, stream>>>(xin_l, n1g + L * 96, n1b + L * 96,
                                            wq + L * 27648, qkvb + L * 288,
                                            bq, bk, bv, shift);
        k_attn<<<NWIN * NHD * 2, 256, 0, stream>>>(bq, bk, bv, relb + L * NBIAS * NHD, hbuf,
                                                   shift ? 1 : 0);
        k_proj<<<TOK / 64, 256, 0, stream>>>(hbuf, wp + L * 9216, projb + L * 96,
                                             xin_l, buf_x, lnb,
                                             n2g + L * 96, n2b + L * 96, shift);
        k_mlp<<<TOK / 64, 256, 0, stream>>>(lnb, buf_x, xfin,
                                            w1 + L * 36864, fc1b + L * 384,
                                            w2 + L * 36864, fc2b + L * 96);
    }
}

// Round 8
// 269.670 us; speedup vs baseline: 6.9086x; 1.0957x over previous
//
#include <hip/hip_runtime.h>
#include <math.h>

#define DIM 96
#define NHD 3
#define HD 32
#define NWT 343          // tokens per window
#define NWIN 128         // b * windows
#define TOK 43904        // total tokens = 2*28^3
#define NBIAS 2197       // (2*7-1)^3
#define SCALE 0.17677669529663687f
#define TPAD 352         // padded token count per window (22 tiles of 16)

typedef __attribute__((ext_vector_type(8))) short bf16x8;
typedef __attribute__((ext_vector_type(4))) float f32x4;

__device__ __forceinline__ unsigned short f2b(float f) {
    union { float f; unsigned int u; } x; x.f = f;
    unsigned int r = (x.u + 0x7fffu + ((x.u >> 16) & 1u)) >> 16;
    return (unsigned short)r;
}
__device__ __forceinline__ unsigned int pk2bf(float a, float b) {
    union { float f; unsigned int u; } x, y; x.f = a; y.f = b;
    return ((x.u + 0x8000u) >> 16) | ((y.u + 0x8000u) & 0xffff0000u);
}

// ---------------- K0: all fp32 -> bf16 weight conversion, one launch --------
// dst layout: [qkvw 55296][projw 18432][fc1w 73728][fc2w 73728] = 221184
__global__ void __launch_bounds__(256) k_cvt4(
        const float* __restrict__ s0, const float* __restrict__ s1,
        const float* __restrict__ s2, const float* __restrict__ s3,
        unsigned short* __restrict__ dst) {
    int i = blockIdx.x * 256 + threadIdx.x;
    if (i >= 221184) return;
    const float* src; int off;
    if (i < 55296)       { src = s0; off = i; }
    else if (i < 73728)  { src = s1; off = i - 55296; }
    else if (i < 147456) { src = s2; off = i - 73728; }
    else                 { src = s3; off = i - 147456; }
    dst[i] = f2b(src[off]);
}

// ---------------- K2: fused LN1 + roll + partition + QKV MFMA ---------------
__global__ void __launch_bounds__(256) k_qkv(
        const float* __restrict__ x, const float* __restrict__ g1,
        const float* __restrict__ b1, const unsigned short* __restrict__ W,
        const float* __restrict__ bias, unsigned short* __restrict__ q,
        unsigned short* __restrict__ k, unsigned short* __restrict__ v, int shift) {
    __shared__ __align__(16) unsigned short lns[64][104];   // 13312 B
    __shared__ __align__(16) unsigned short wbuf[96][104];  // 19968 B
    int wid = threadIdx.x >> 6, lane = threadIdx.x & 63;
    int lm = lane & 15, q4 = lane >> 4;
    int m0 = blockIdx.x * 64 + wid * 16;
    int bwr[4], nnr[4];
    size_t rowoff[4];
    #pragma unroll
    for (int r = 0; r < 4; ++r) {
        int wtok = m0 + q4 * 4 + r;
        int bw = wtok / NWT, n = wtok % NWT;
        bwr[r] = bw; nnr[r] = n;
        int b = bw >> 6, win = bw & 63;
        int wdi = win >> 4, whi = (win >> 2) & 3, wwi = win & 3;
        int d = n / 49, h = (n / 7) % 7, w = n % 7;
        int sd = (wdi * 7 + d + shift) % 28;
        int sh = (whi * 7 + h + shift) % 28;
        int sw = (wwi * 7 + w + shift) % 28;
        rowoff[r] = (((size_t)(b * 28 + sd) * 28 + sh) * 28 + sw) * 96;
    }
    float val[6][4], g1v[6], b1v[6];
    #pragma unroll
    for (int c = 0; c < 6; ++c) {
        int ncol = c * 16 + lm;
        g1v[c] = g1[ncol]; b1v[c] = b1[ncol];
        #pragma unroll
        for (int r = 0; r < 4; ++r) val[c][r] = x[rowoff[r] + ncol];
    }
    #pragma unroll
    for (int r = 0; r < 4; ++r) {
        float s = 0.f, s2 = 0.f;
        #pragma unroll
        for (int c = 0; c < 6; ++c) { s += val[c][r]; s2 += val[c][r] * val[c][r]; }
        #pragma unroll
        for (int off = 8; off > 0; off >>= 1) {
            s  += __shfl_xor(s,  off, 64);
            s2 += __shfl_xor(s2, off, 64);
        }
        float mu = s * (1.0f / 96.0f);
        float rstd = rsqrtf(s2 * (1.0f / 96.0f) - mu * mu + 1e-5f);
        int row = wid * 16 + q4 * 4 + r;
        #pragma unroll
        for (int c = 0; c < 6; ++c)
            lns[row][c * 16 + lm] = f2b((val[c][r] - mu) * rstd * g1v[c] + b1v[c]);
    }
    __syncthreads();
    bf16x8 a1[3];
    #pragma unroll
    for (int ks = 0; ks < 3; ++ks)
        a1[ks] = *((const bf16x8*)&lns[wid * 16 + lm][ks * 32 + q4 * 8]);
    for (int ch = 0; ch < 3; ++ch) {
        __syncthreads();
        const uint4* src = (const uint4*)(W + ch * 96 * 96);
        for (int s = threadIdx.x; s < 1152; s += 256) {
            int row = s / 12, seg = s % 12;
            *((uint4*)&wbuf[row][seg * 8]) = src[s];
        }
        __syncthreads();
        f32x4 acc[6];
        #pragma unroll
        for (int c = 0; c < 6; ++c) acc[c] = (f32x4){0.f, 0.f, 0.f, 0.f};
        #pragma unroll
        for (int ks = 0; ks < 3; ++ks) {
            #pragma unroll
            for (int c = 0; c < 6; ++c) {
                bf16x8 b = *((const bf16x8*)&wbuf[c * 16 + lm][ks * 32 + q4 * 8]);
                acc[c] = __builtin_amdgcn_mfma_f32_16x16x32_bf16(a1[ks], b, acc[c], 0, 0, 0);
            }
        }
        #pragma unroll
        for (int c = 0; c < 6; ++c) {
            int col = c * 16 + lm;
            int head = col >> 5, hd = col & 31;
            float bb = bias[ch * 96 + col];
            #pragma unroll
            for (int r = 0; r < 4; ++r) {
                int wh = bwr[r] * NHD + head;
                float vv = acc[c][r] + bb;
                if (ch == 0)
                    q[(size_t)wh * (TPAD * 32) + nnr[r] * 32 + hd] = f2b(vv * SCALE);
                else if (ch == 1)
                    k[(size_t)wh * (TPAD * 32) + nnr[r] * 32 + hd] = f2b(vv);
                else
                    v[(size_t)wh * (32 * TPAD) + hd * TPAD + nnr[r]] = f2b(vv);
            }
        }
    }
}

// ---------------- K3: MFMA flash attention, pair-interleaved q-tiles --------
// grid = NWIN*NHD*3; block = 256 (4 waves); each wave: 2 q-tiles simultaneously
__global__ void __launch_bounds__(256) k_attn(
        const unsigned short* __restrict__ q, const unsigned short* __restrict__ k,
        const unsigned short* __restrict__ vT, const float* __restrict__ rel,
        unsigned short* __restrict__ o, int shifted) {
    __shared__ float relh[NBIAS];
    __shared__ int   jinfo[NWT];
    __shared__ __align__(16) unsigned short vts[32 * 360];
    __shared__ __align__(16) unsigned short pbuf[4][2][16 * 40];
    __shared__ float dnm[4][2][16];
    int wh = blockIdx.x / 3, third = blockIdx.x % 3;
    int bw = wh / NHD, head = wh % NHD;
    for (int i = threadIdx.x; i < NBIAS; i += 256) relh[i] = rel[i * NHD + head];
    const unsigned int* vsrc = (const unsigned int*)(vT + (size_t)wh * 32 * TPAD);
    unsigned int* vdst = (unsigned int*)vts;
    for (int i = threadIdx.x; i < 32 * 176; i += 256) {
        int row = i / 176, cc = i - row * 176;
        vdst[row * 180 + cc] = vsrc[i];
    }
    int win = bw & 63;
    int wdi = win >> 4, whi = (win >> 2) & 3, wwi = win & 3;
    for (int i = threadIdx.x; i < NWT; i += 256) {
        int d = i / 49, h = (i / 7) % 7, w = i % 7;
        int gd = wdi * 7 + d, gh = whi * 7 + h, gw = wwi * 7 + w;
        int rd = (gd < 21) ? 0 : ((gd < 25) ? 1 : 2);
        int rh = (gh < 21) ? 0 : ((gh < 25) ? 1 : 2);
        int rw = (gw < 21) ? 0 : ((gw < 25) ? 1 : 2);
        jinfo[i] = (d * 169 + h * 13 + w) | ((rd * 9 + rh * 3 + rw) << 16);
    }
    __syncthreads();
    int wid = threadIdx.x >> 6, lane = threadIdx.x & 63;
    int lm = lane & 15, q4 = lane >> 4;
    int tb = third * 8 + wid * 2;       // tiles {tb, tb+1} of 22
    if (tb > 21) return;                // no barriers below — safe early exit
    bool dual = (tb + 1 <= 21);
    int qtA = tb, qtB = dual ? tb + 1 : tb;
    const unsigned short* qbase = q + (size_t)wh * TPAD * 32;
    const unsigned short* kbase = k + (size_t)wh * TPAD * 32;
    int qtokA = qtA * 16 + lm, qtokB = qtB * 16 + lm;
    bf16x8 qfA = *((const bf16x8*)(qbase + qtokA * 32 + q4 * 8));
    bf16x8 qfB = *((const bf16x8*)(qbase + qtokB * 32 + q4 * 8));
    int jqA = jinfo[min(qtokA, NWT - 1)], jqB = jinfo[min(qtokB, NWT - 1)];
    int jqcA = (jqA & 0xffff) + 1098, rqA = jqA >> 16;
    int jqcB = (jqB & 0xffff) + 1098, rqB = jqB >> 16;
    f32x4 aA0 = (f32x4){0.f,0.f,0.f,0.f}, aA1 = aA0, aB0 = aA0, aB1 = aA0;
    float dA = 0.f, dB = 0.f;
    unsigned short* pbA = pbuf[wid][0];
    unsigned short* pbB = pbuf[wid][1];
    for (int pr = 0; pr < 11; ++pr) {
        int kb0 = pr * 32;
        bf16x8 kf0 = *((const bf16x8*)(kbase + (kb0 + lm) * 32 + q4 * 8));
        bf16x8 kf1 = *((const bf16x8*)(kbase + (kb0 + 16 + lm) * 32 + q4 * 8));
        f32x4 z = (f32x4){0.f, 0.f, 0.f, 0.f};
        f32x4 sA0 = __builtin_amdgcn_mfma_f32_16x16x32_bf16(kf0, qfA, z, 0, 0, 0);
        f32x4 sA1 = __builtin_amdgcn_mfma_f32_16x16x32_bf16(kf1, qfA, z, 0, 0, 0);
        f32x4 sB0 = __builtin_amdgcn_mfma_f32_16x16x32_bf16(kf0, qfB, z, 0, 0, 0);
        f32x4 sB1 = __builtin_amdgcn_mfma_f32_16x16x32_bf16(kf1, qfB, z, 0, 0, 0);
        float pA[8], pB[8];
        #pragma unroll
        for (int t = 0; t < 2; ++t) {
            #pragma unroll
            for (int r = 0; r < 4; ++r) {
                int key = kb0 + t * 16 + q4 * 4 + r;
                int jk = jinfo[min(key, NWT - 1)];
                int jkc = jk & 0xffff, rk = jk >> 16;
                bool pad = key >= NWT;
                float sA_ = (t ? sA1[r] : sA0[r]) + relh[jqcA - jkc];
                if (shifted && (rk != rqA)) sA_ -= 100.0f;
                float pvA = pad ? 0.0f : __expf(sA_);
                dA += pvA; pA[t * 4 + r] = pvA;
                float sB_ = (t ? sB1[r] : sB0[r]) + relh[jqcB - jkc];
                if (shifted && (rk != rqB)) sB_ -= 100.0f;
                float pvB = pad ? 0.0f : __expf(sB_);
                dB += pvB; pB[t * 4 + r] = pvB;
            }
        }
        #pragma unroll
        for (int t = 0; t < 2; ++t) {
            *((unsigned int*)(pbA + lm * 40 + t * 16 + q4 * 4)) =
                pk2bf(pA[t * 4 + 0], pA[t * 4 + 1]);
            *((unsigned int*)(pbA + lm * 40 + t * 16 + q4 * 4 + 2)) =
                pk2bf(pA[t * 4 + 2], pA[t * 4 + 3]);
            *((unsigned int*)(pbB + lm * 40 + t * 16 + q4 * 4)) =
                pk2bf(pB[t * 4 + 0], pB[t * 4 + 1]);
            *((unsigned int*)(pbB + lm * 40 + t * 16 + q4 * 4 + 2)) =
                pk2bf(pB[t * 4 + 2], pB[t * 4 + 3]);
        }
        bf16x8 pfA = *((const bf16x8*)(pbA + lm * 40 + q4 * 8));
        bf16x8 pfB = *((const bf16x8*)(pbB + lm * 40 + q4 * 8));
        bf16x8 v0 = *((const bf16x8*)(vts + lm * 360 + kb0 + q4 * 8));
        bf16x8 v1 = *((const bf16x8*)(vts + (16 + lm) * 360 + kb0 + q4 * 8));
        aA0 = __builtin_amdgcn_mfma_f32_16x16x32_bf16(pfA, v0, aA0, 0, 0, 0);
        aA1 = __builtin_amdgcn_mfma_f32_16x16x32_bf16(pfA, v1, aA1, 0, 0, 0);
        aB0 = __builtin_amdgcn_mfma_f32_16x16x32_bf16(pfB, v0, aB0, 0, 0, 0);
        aB1 = __builtin_amdgcn_mfma_f32_16x16x32_bf16(pfB, v1, aB1, 0, 0, 0);
    }
    dA += __shfl_xor(dA, 16, 64); dA += __shfl_xor(dA, 32, 64);
    dB += __shfl_xor(dB, 16, 64); dB += __shfl_xor(dB, 32, 64);
    if (lane < 16) { dnm[wid][0][lm] = dA; dnm[wid][1][lm] = dB; }
    #pragma unroll
    for (int r = 0; r < 4; ++r) {
        int qrowA = qtA * 16 + q4 * 4 + r;
        if (qrowA < NWT) {
            float inv = 1.0f / dnm[wid][0][q4 * 4 + r];
            unsigned short* op = o + (size_t)(bw * NWT + qrowA) * DIM + head * HD;
            op[lm]      = f2b(aA0[r] * inv);
            op[16 + lm] = f2b(aA1[r] * inv);
        }
    }
    if (dual) {
        #pragma unroll
        for (int r = 0; r < 4; ++r) {
            int qrowB = qtB * 16 + q4 * 4 + r;
            if (qrowB < NWT) {
                float inv = 1.0f / dnm[wid][1][q4 * 4 + r];
                unsigned short* op = o + (size_t)(bw * NWT + qrowB) * DIM + head * HD;
                op[lm]      = f2b(aB0[r] * inv);
                op[16 + lm] = f2b(aB1[r] * inv);
            }
        }
    }
}

// ---------------- K4: fused proj + reverse/roll + residual + LN2 + MLP ------
// big[] layout: proj phase: W[96][104] (9984 sh). mlp phase: w1s[64][104]@0,
// w2s[96][76]@6656, hid[4][16*76]@13952. lns separate.
__global__ void __launch_bounds__(256) k_pm(
        const unsigned short* __restrict__ ao, const unsigned short* __restrict__ Wp,
        const float* __restrict__ pbias, const float* __restrict__ xin,
        float* __restrict__ xout,
        const float* __restrict__ g2, const float* __restrict__ b2,
        const unsigned short* __restrict__ w1, const float* __restrict__ bb1,
        const unsigned short* __restrict__ w2, const float* __restrict__ bb2,
        int shift) {
    __shared__ __align__(16) unsigned short lns[64][104];   // 13312 B
    __shared__ __align__(16) unsigned short big[18816];     // 37632 B
    int wid = threadIdx.x >> 6, lane = threadIdx.x & 63;
    int lm = lane & 15, q4 = lane >> 4;
    int m0 = blockIdx.x * 64 + wid * 16;
    // stage proj W
    for (int s = threadIdx.x; s < 1152; s += 256) {
        int row = s / 12, seg = s % 12;
        *((uint4*)&big[row * 104 + seg * 8]) = ((const uint4*)Wp)[s];
    }
    const unsigned short* arow = ao + (size_t)(m0 + lm) * 96;
    bf16x8 a1[3];
    #pragma unroll
    for (int ks = 0; ks < 3; ++ks)
        a1[ks] = *((const bf16x8*)(arow + ks * 32 + q4 * 8));
    __syncthreads();
    f32x4 acc[6];
    #pragma unroll
    for (int c = 0; c < 6; ++c) acc[c] = (f32x4){0.f, 0.f, 0.f, 0.f};
    #pragma unroll
    for (int ks = 0; ks < 3; ++ks) {
        #pragma unroll
        for (int c = 0; c < 6; ++c) {
            bf16x8 b = *((const bf16x8*)&big[(c * 16 + lm) * 104 + ks * 32 + q4 * 8]);
            acc[c] = __builtin_amdgcn_mfma_f32_16x16x32_bf16(a1[ks], b, acc[c], 0, 0, 0);
        }
    }
    size_t rowoff[4];
    #pragma unroll
    for (int r = 0; r < 4; ++r) {
        int wtok = m0 + q4 * 4 + r;
        int bw = wtok / NWT, n = wtok % NWT;
        int b = bw >> 6, win = bw & 63;
        int wdi = win >> 4, whi = (win >> 2) & 3, wwi = win & 3;
        int d = n / 49, h = (n / 7) % 7, w = n % 7;
        int sd = (wdi * 7 + d + shift) % 28;
        int sh = (whi * 7 + h + shift) % 28;
        int sw = (wwi * 7 + w + shift) % 28;
        rowoff[r] = (((size_t)(b * 28 + sd) * 28 + sh) * 28 + sw) * 96;
    }
    float val[6][4], g2v[6], b2v[6];
    #pragma unroll
    for (int c = 0; c < 6; ++c) {
        int n = c * 16 + lm;
        float bb = pbias[n];
        g2v[c] = g2[n]; b2v[c] = b2[n];
        #pragma unroll
        for (int r = 0; r < 4; ++r)
            val[c][r] = xin[rowoff[r] + n] + acc[c][r] + bb;   // y (kept in regs)
    }
    // LN2 -> lns (this wave's own 16 rows only; no barrier needed)
    #pragma unroll
    for (int r = 0; r < 4; ++r) {
        float s = 0.f, s2 = 0.f;
        #pragma unroll
        for (int c = 0; c < 6; ++c) { s += val[c][r]; s2 += val[c][r] * val[c][r]; }
        #pragma unroll
        for (int off = 8; off > 0; off >>= 1) {
            s  += __shfl_xor(s,  off, 64);
            s2 += __shfl_xor(s2, off, 64);
        }
        float mu = s * (1.0f / 96.0f);
        float rstd = rsqrtf(s2 * (1.0f / 96.0f) - mu * mu + 1e-5f);
        int row = wid * 16 + q4 * 4 + r;
        #pragma unroll
        for (int c = 0; c < 6; ++c)
            lns[row][c * 16 + lm] = f2b((val[c][r] - mu) * rstd * g2v[c] + b2v[c]);
    }
    bf16x8 am[3];
    #pragma unroll
    for (int ks = 0; ks < 3; ++ks)
        am[ks] = *((const bf16x8*)&lns[wid * 16 + lm][ks * 32 + q4 * 8]);
    f32x4 acc2[6];
    #pragma unroll
    for (int c = 0; c < 6; ++c) acc2[c] = (f32x4){0.f, 0.f, 0.f, 0.f};
    unsigned short* hid_ = &big[13952 + wid * 1216];
    for (int ch = 0; ch < 6; ++ch) {
        __syncthreads();
        const uint4* src1 = (const uint4*)(w1 + ch * 64 * 96);
        #pragma unroll
        for (int t = 0; t < 3; ++t) {
            int s = threadIdx.x + t * 256;
            int row = s / 12, seg = s % 12;
            *((uint4*)&big[row * 104 + seg * 8]) = src1[s];
        }
        #pragma unroll
        for (int t = 0; t < 3; ++t) {
            int s = threadIdx.x + t * 256;
            int row = s >> 3, seg = s & 7;
            *((uint4*)&big[6656 + row * 76 + seg * 8]) =
                *((const uint4*)(w2 + row * 384 + ch * 64 + seg * 8));
        }
        __syncthreads();
        f32x4 acc1[4];
        #pragma unroll
        for (int t = 0; t < 4; ++t) acc1[t] = (f32x4){0.f, 0.f, 0.f, 0.f};
        #pragma unroll
        for (int ks = 0; ks < 3; ++ks) {
            #pragma unroll
            for (int t = 0; t < 4; ++t) {
                bf16x8 b = *((const bf16x8*)&big[(t * 16 + lm) * 104 + ks * 32 + q4 * 8]);
                acc1[t] = __builtin_amdgcn_mfma_f32_16x16x32_bf16(am[ks], b, acc1[t], 0, 0, 0);
            }
        }
        #pragma unroll
        for (int t = 0; t < 4; ++t) {
            float bb = bb1[ch * 64 + t * 16 + lm];
            #pragma unroll
            for (int r = 0; r < 4; ++r) {
                float v2 = acc1[t][r] + bb;
                float ge = 0.5f * v2 * (1.0f + erff(v2 * 0.70710678118654752f));
                hid_[(q4 * 4 + r) * 76 + t * 16 + lm] = f2b(ge);
            }
        }
        #pragma unroll
        for (int ks2 = 0; ks2 < 2; ++ks2) {
            bf16x8 a = *((const bf16x8*)(hid_ + lm * 76 + ks2 * 32 + q4 * 8));
            #pragma unroll
            for (int c = 0; c < 6; ++c) {
                bf16x8 b = *((const bf16x8*)&big[6656 + (c * 16 + lm) * 76 + ks2 * 32 + q4 * 8]);
                acc2[c] = __builtin_amdgcn_mfma_f32_16x16x32_bf16(a, b, acc2[c], 0, 0, 0);
            }
        }
    }
    #pragma unroll
    for (int c = 0; c < 6; ++c) {
        int n = c * 16 + lm;
        float bb = bb2[n];
        #pragma unroll
        for (int r = 0; r < 4; ++r)
            xout[rowoff[r] + n] = val[c][r] + acc2[c][r] + bb;
    }
}

extern "C" void kernel_launch(void* const* d_in, const int* in_sizes, int n_in,
                              void* d_out, int out_size, void* d_ws, size_t ws_size,
                              hipStream_t stream) {
    const float* x     = (const float*)d_in[0];
    const float* n1g   = (const float*)d_in[1];
    const float* n1b   = (const float*)d_in[2];
    const float* qkvw  = (const float*)d_in[3];
    const float* qkvb  = (const float*)d_in[4];
    const float* relb  = (const float*)d_in[5];
    const float* projw = (const float*)d_in[6];
    const float* projb = (const float*)d_in[7];
    const float* n2g   = (const float*)d_in[8];
    const float* n2b   = (const float*)d_in[9];
    const float* fc1w  = (const float*)d_in[10];
    const float* fc1b  = (const float*)d_in[11];
    const float* fc2w  = (const float*)d_in[12];
    const float* fc2b  = (const float*)d_in[13];
    float* out = (float*)d_out;

    const size_t NEL = (size_t)TOK * DIM;
    const size_t QKN = (size_t)NWIN * NHD * TPAD * 32;
    float* buf_x = (float*)d_ws;
    unsigned short* hbuf = (unsigned short*)(buf_x + NEL);  // attn out bf16 [tok][96]
    unsigned short* bq   = hbuf + NEL;       // [wh][352][32]
    unsigned short* bk   = bq + QKN;         // [wh][352][32]
    unsigned short* bv   = bk + QKN;         // [wh][32][352]  (V^T)
    unsigned short* wts  = bv + QKN;
    unsigned short* wq  = wts;                 // 2 x 27648
    unsigned short* wp  = wq + 2 * 27648;      // 2 x 9216
    unsigned short* w1  = wp + 2 * 9216;       // 2 x 36864
    unsigned short* w2  = w1 + 2 * 36864;      // 2 x 36864

    k_cvt4<<<(221184 + 255) / 256, 256, 0, stream>>>(qkvw, projw, fc1w, fc2w, wts);

    for (int L = 0; L < 2; ++L) {
        int shift = (L == 0) ? 0 : 3;
        const float* xin_l = (L == 0) ? x : buf_x;
        float* xfin = (L == 0) ? buf_x : out;

        k_qkv<<<TOK / 64, 256, 0, stream>>>(xin_l, n1g + L * 96, n1b + L * 96,
                                            wq + L * 27648, qkvb + L * 288,
                                            bq, bk, bv, shift);
        k_attn<<<NWIN * NHD * 3, 256, 0, stream>>>(bq, bk, bv, relb + L * NBIAS * NHD, hbuf,
                                                   shift ? 1 : 0);
        k_pm<<<TOK / 64, 256, 0, stream>>>(hbuf, wp + L * 9216, projb + L * 96,
                                           xin_l, xfin,
                                           n2g + L * 96, n2b + L * 96,
                                           w1 + L * 36864, fc1b + L * 384,
                                           w2 + L * 36864, fc2b + L * 96, shift);
    }
}